// Round 1
// baseline (10587.224 us; speedup 1.0000x reference)
//
#include <hip/hip_runtime.h>

// MultiLayerLSTM: B=256, T=1024, V=27, E=64, H=128 (4H=512)
// Round 1: correctness-first persistent kernel.
//  - table0[v][512] = emb[v]@wx0 + b0 precomputed (V=27 -> tiny table)
//  - 128 blocks x 512 threads; each block owns 2 batch elements for all T steps
//  - state (h,c) lives in LDS; weights streamed from L2 each step (768 KB/step)
//  - gate order matches jnp.split(.,4,axis=1): f, i, g, o
//    c = sig(f)*c + sig(i)*tanh(g);  h = tanh(c)*sig(o)

#define B_  256
#define T_  1024
#define V_  27
#define E_  64
#define H_  128
#define G4  512   // 4*H

__device__ __forceinline__ float sigf(float x) { return 1.0f / (1.0f + expf(-x)); }

__global__ __launch_bounds__(G4)
void build_table0(const float* __restrict__ emb,
                  const float* __restrict__ wx0,
                  const float* __restrict__ b0,
                  float* __restrict__ table0)
{
    const int v = blockIdx.x;        // 0..26
    const int j = threadIdx.x;       // 0..511
    __shared__ float e[E_];
    if (j < E_) e[j] = emb[v * E_ + j];
    __syncthreads();
    float s = b0[j];
#pragma unroll 8
    for (int k = 0; k < E_; ++k) s += e[k] * wx0[k * G4 + j];
    table0[v * G4 + j] = s;
}

__global__ __launch_bounds__(G4, 1)
void lstm_persist(const int* __restrict__ x,
                  const float* __restrict__ table0,
                  const float* __restrict__ wh0,
                  const float* __restrict__ wx1,
                  const float* __restrict__ wh1,
                  const float* __restrict__ b1,
                  const float* __restrict__ why,
                  const float* __restrict__ by,
                  float* __restrict__ out)
{
    const int j  = threadIdx.x;       // gate column 0..511
    const int bb = blockIdx.x * 2;    // first batch index of this block's pair

    __shared__ float h0s[2][H_], c0s[2][H_], h1s[2][H_], c1s[2][H_];
    __shared__ float hcat[2][2 * H_];           // [h0_new ; h1_prev] per batch
    __shared__ float g0s[2][G4], g1s[2][G4];
    __shared__ float whyS[H_ * V_];             // 13.8 KB
    __shared__ float b1S[G4];
    __shared__ float byS[V_];
    __shared__ float pb[2][V_][8];              // y-proj partials

    // one-time LDS preload + state init
    for (int i = j; i < H_ * V_; i += G4) whyS[i] = why[i];
    b1S[j] = b1[j];
    if (j < V_) byS[j] = by[j];
    if (j < H_) {
        h0s[0][j] = 0.f; h0s[1][j] = 0.f; c0s[0][j] = 0.f; c0s[1][j] = 0.f;
        h1s[0][j] = 0.f; h1s[1][j] = 0.f; c1s[0][j] = 0.f; c1s[1][j] = 0.f;
    }
    __syncthreads();

    const int* xA = x + (size_t)(bb + 0) * T_;
    const int* xB = x + (size_t)(bb + 1) * T_;
    float* outA = out + (size_t)(bb + 0) * T_ * V_;
    float* outB = out + (size_t)(bb + 1) * T_ * V_;

    for (int t = 0; t < T_; ++t) {
        const int ia = xA[t];
        const int ib = xB[t];

        // ---- layer 0 gates: table row + h0 @ wh0 ----
        float aA = table0[ia * G4 + j];
        float aB = table0[ib * G4 + j];
#pragma unroll 8
        for (int k = 0; k < H_; ++k) {
            const float w = wh0[k * G4 + j];
            aA += h0s[0][k] * w;
            aB += h0s[1][k] * w;
        }
        g0s[0][j] = aA; g0s[1][j] = aB;
        __syncthreads();

        // ---- layer 0 cell update (256 threads: 2 batches x 128 rows) ----
        if (j < 2 * H_) {
            const int gi = j >> 7, r = j & (H_ - 1);
            const float f  = sigf(g0s[gi][r]);
            const float i_ = sigf(g0s[gi][H_ + r]);
            const float g  = tanhf(g0s[gi][2 * H_ + r]);
            const float o  = sigf(g0s[gi][3 * H_ + r]);
            const float c  = f * c0s[gi][r] + i_ * g;
            c0s[gi][r] = c;
            const float h = tanhf(c) * o;
            h0s[gi][r] = h;
            hcat[gi][r] = h;
            hcat[gi][H_ + r] = h1s[gi][r];   // h1_prev (not yet updated this step)
        }
        __syncthreads();

        // ---- layer 1 gates: b1 + h0_new @ wx1 + h1_prev @ wh1 ----
        float bA = b1S[j];
        float bB = bA;
#pragma unroll 8
        for (int k = 0; k < H_; ++k) {
            const float w = wx1[k * G4 + j];
            bA += hcat[0][k] * w;
            bB += hcat[1][k] * w;
        }
#pragma unroll 8
        for (int k = 0; k < H_; ++k) {
            const float w = wh1[k * G4 + j];
            bA += hcat[0][H_ + k] * w;
            bB += hcat[1][H_ + k] * w;
        }
        g1s[0][j] = bA; g1s[1][j] = bB;
        __syncthreads();

        // ---- layer 1 cell update ----
        if (j < 2 * H_) {
            const int gi = j >> 7, r = j & (H_ - 1);
            const float f  = sigf(g1s[gi][r]);
            const float i_ = sigf(g1s[gi][H_ + r]);
            const float g  = tanhf(g1s[gi][2 * H_ + r]);
            const float o  = sigf(g1s[gi][3 * H_ + r]);
            const float c  = f * c1s[gi][r] + i_ * g;
            c1s[gi][r] = c;
            h1s[gi][r] = tanhf(c) * o;
        }
        __syncthreads();

        // ---- output projection: y = h1 @ why + by (27 outputs/batch) ----
        // 432 threads: 2 batches x 27 vocab x 8 partial-threads (16 elems each)
        if (j < 2 * V_ * 8) {
            int q = j;
            const int gi = (q >= V_ * 8) ? 1 : 0;
            q -= gi * V_ * 8;
            const int v = q >> 3, kk = q & 7;
            float p = 0.f;
#pragma unroll
            for (int k = kk * 16; k < kk * 16 + 16; ++k)
                p += h1s[gi][k] * whyS[k * V_ + v];
            pb[gi][v][kk] = p;
        }
        __syncthreads();

        if (j < 2 * V_) {
            const int gi = (j >= V_) ? 1 : 0;
            const int v  = j - gi * V_;
            float s = byS[v];
#pragma unroll
            for (int q = 0; q < 8; ++q) s += pb[gi][v][q];
            (gi ? outB : outA)[t * V_ + v] = s;
        }
        __syncthreads();   // protect g0s/pb before next iteration overwrites
    }
}

extern "C" void kernel_launch(void* const* d_in, const int* in_sizes, int n_in,
                              void* d_out, int out_size, void* d_ws, size_t ws_size,
                              hipStream_t stream)
{
    const int*   x   = (const int*)  d_in[0];
    const float* emb = (const float*)d_in[1];
    const float* wx0 = (const float*)d_in[2];
    const float* wh0 = (const float*)d_in[3];
    const float* b0  = (const float*)d_in[4];
    const float* wx1 = (const float*)d_in[5];
    const float* wh1 = (const float*)d_in[6];
    const float* b1  = (const float*)d_in[7];
    const float* why = (const float*)d_in[8];
    const float* by  = (const float*)d_in[9];
    float* out    = (float*)d_out;
    float* table0 = (float*)d_ws;   // 27*512 floats = 55296 B

    build_table0<<<dim3(V_), dim3(G4), 0, stream>>>(emb, wx0, b0, table0);
    lstm_persist<<<dim3(B_ / 2), dim3(G4), 0, stream>>>(
        x, table0, wh0, wx1, wh1, b1, why, by, out);
}

// Round 2
// 6789.016 us; speedup vs baseline: 1.5595x; 1.5595x over previous
//
#include <hip/hip_runtime.h>

// MultiLayerLSTM: B=256, T=1024, V=27, E=64, H=128 (4H=512)
// Round 2: 3-phase decomposition, weights register-resident in recurrent phases.
//   P0: table0[v][512] = emb[v]@wx0 + b0
//   P1: layer-0 recurrence, wh0 in VGPRs (128/thread), h0 -> ws
//   P2: GEMM xg1 = h0 @ wx1 + b1 (batched over (b,t))
//   P3: layer-1 recurrence, wh1 in VGPRs, y = h1@why+by pipelined 1 step behind
// Time chunked to fit ws; falls back to round-1 streaming kernel if ws too small.

#define B_  256
#define T_  1024
#define V_  27
#define E_  64
#define H_  128
#define G4  512   // 4*H

__device__ __forceinline__ float sigf(float x) { return 1.0f / (1.0f + expf(-x)); }

// ---------------- P0: token table ----------------
__global__ __launch_bounds__(G4)
void build_table0(const float* __restrict__ emb,
                  const float* __restrict__ wx0,
                  const float* __restrict__ b0,
                  float* __restrict__ table0)
{
    const int v = blockIdx.x;        // 0..26
    const int j = threadIdx.x;       // 0..511
    __shared__ float e[E_];
    if (j < E_) e[j] = emb[v * E_ + j];
    __syncthreads();
    float s = b0[j];
#pragma unroll 8
    for (int k = 0; k < E_; ++k) s += e[k] * wx0[k * G4 + j];
    table0[v * G4 + j] = s;
}

// ---------------- P1: layer-0 recurrence (wh0 in registers) ----------------
__global__ __launch_bounds__(G4, 2)
void lstm_l0_chunk(const int* __restrict__ x,
                   const float* __restrict__ table0,
                   const float* __restrict__ wh0,
                   float* __restrict__ h0st, float* __restrict__ c0st,
                   float* __restrict__ h0buf,
                   int t0, int TC)
{
    const int j = threadIdx.x;
    const int b = blockIdx.x;

    __shared__ __align__(16) float hS[H_];
    __shared__ float cS[H_];
    __shared__ float gS[G4];
    __shared__ float tabS[V_ * G4];   // 55296 B

    float w[H_];
#pragma unroll
    for (int k = 0; k < H_; ++k) w[k] = wh0[k * G4 + j];
    for (int e = j; e < V_ * G4; e += G4) tabS[e] = table0[e];
    if (j < H_) { hS[j] = h0st[b * H_ + j]; cS[j] = c0st[b * H_ + j]; }
    __syncthreads();

    const int* xb = x + (size_t)b * T_ + t0;
    float* hob = h0buf + (size_t)b * TC * H_;

    int idx_next = xb[0];
    for (int t = 0; t < TC; ++t) {
        const int idx = idx_next;
        if (t + 1 < TC) idx_next = xb[t + 1];

        float a0 = 0.f, a1 = 0.f, a2 = 0.f, a3 = 0.f;
        const float tv = tabS[idx * G4 + j];
        const float4* hv4 = reinterpret_cast<const float4*>(hS);
#pragma unroll
        for (int k4 = 0; k4 < H_ / 4; ++k4) {
            const float4 hv = hv4[k4];
            a0 = fmaf(hv.x, w[4 * k4 + 0], a0);
            a1 = fmaf(hv.y, w[4 * k4 + 1], a1);
            a2 = fmaf(hv.z, w[4 * k4 + 2], a2);
            a3 = fmaf(hv.w, w[4 * k4 + 3], a3);
        }
        gS[j] = ((a0 + a1) + (a2 + a3)) + tv;
        __syncthreads();

        if (j < H_) {
            const float f  = sigf(gS[j]);
            const float i_ = sigf(gS[H_ + j]);
            const float g  = tanhf(gS[2 * H_ + j]);
            const float o  = sigf(gS[3 * H_ + j]);
            const float c  = f * cS[j] + i_ * g;
            cS[j] = c;
            const float h = tanhf(c) * o;
            hS[j] = h;
            hob[(size_t)t * H_ + j] = h;
        }
        __syncthreads();
    }
    if (j < H_) { h0st[b * H_ + j] = hS[j]; c0st[b * H_ + j] = cS[j]; }
}

// ---------------- P2: xg1 = h0 @ wx1 + b1 ----------------
// block: 64 rows x 512 cols; thread: 16 rows x 4 cols (acc[4][16])
__global__ __launch_bounds__(G4, 4)
void gemm_xg1(const float* __restrict__ h0buf,
              const float* __restrict__ wx1,
              const float* __restrict__ b1,
              float* __restrict__ xg1)
{
    const int j  = threadIdx.x;
    const size_t m0 = (size_t)blockIdx.x * 64;
    const int c  = j & 127;          // cols c, c+128, c+256, c+384
    const int rg = j >> 7;           // rows rg*16 .. rg*16+15

    __shared__ __align__(16) float aT[64 * 132];   // row-major [r][k], pad 132

    // load A tile 64x128 (float4 coalesced)
#pragma unroll
    for (int i = 0; i < 4; ++i) {
        const int e  = i * G4 + j;       // float4 index 0..2047
        const int r  = e >> 5;           // 32 float4 per row
        const int k4 = e & 31;
        const float4 v = *reinterpret_cast<const float4*>(&h0buf[(m0 + r) * H_ + k4 * 4]);
        *reinterpret_cast<float4*>(&aT[r * 132 + k4 * 4]) = v;
    }
    __syncthreads();

    float acc[4][16];
#pragma unroll
    for (int cc = 0; cc < 4; ++cc)
#pragma unroll
        for (int rr = 0; rr < 16; ++rr) acc[cc][rr] = 0.f;

    for (int k4 = 0; k4 < 32; ++k4) {
        float bv[4][4];   // [kk][cc]
#pragma unroll
        for (int kk = 0; kk < 4; ++kk)
#pragma unroll
            for (int cc = 0; cc < 4; ++cc)
                bv[kk][cc] = wx1[(size_t)(k4 * 4 + kk) * G4 + cc * 128 + c];
#pragma unroll
        for (int rr = 0; rr < 16; ++rr) {
            const float4 av = *reinterpret_cast<const float4*>(&aT[(rg * 16 + rr) * 132 + k4 * 4]);
#pragma unroll
            for (int cc = 0; cc < 4; ++cc) {
                acc[cc][rr] = fmaf(av.x, bv[0][cc], acc[cc][rr]);
                acc[cc][rr] = fmaf(av.y, bv[1][cc], acc[cc][rr]);
                acc[cc][rr] = fmaf(av.z, bv[2][cc], acc[cc][rr]);
                acc[cc][rr] = fmaf(av.w, bv[3][cc], acc[cc][rr]);
            }
        }
    }

    float b1v[4];
#pragma unroll
    for (int cc = 0; cc < 4; ++cc) b1v[cc] = b1[cc * 128 + c];
#pragma unroll
    for (int rr = 0; rr < 16; ++rr) {
        const size_t row = m0 + rg * 16 + rr;
#pragma unroll
        for (int cc = 0; cc < 4; ++cc)
            xg1[row * G4 + cc * 128 + c] = acc[cc][rr] + b1v[cc];
    }
}

// ---------------- P3: layer-1 recurrence (wh1 in registers) + y ----------------
__global__ __launch_bounds__(G4, 2)
void lstm_l1_chunk(const float* __restrict__ xg1,
                   const float* __restrict__ wh1,
                   const float* __restrict__ why,
                   const float* __restrict__ by,
                   float* __restrict__ h1st, float* __restrict__ c1st,
                   float* __restrict__ out,
                   int t0, int TC)
{
    const int j = threadIdx.x;
    const int b = blockIdx.x;

    __shared__ __align__(16) float hS[H_];
    __shared__ float cS[H_];
    __shared__ float gS[G4];
    __shared__ __align__(16) float whyT[V_ * 132];  // [v][k] pad 132
    __shared__ __align__(16) float pb[V_][8];

    float w[H_];
#pragma unroll
    for (int k = 0; k < H_; ++k) w[k] = wh1[k * G4 + j];
    for (int e = j; e < V_ * H_; e += G4) whyT[(e % V_) * 132 + e / V_] = why[e];
    const float byv = (j >= 256 && j < 256 + V_) ? by[j - 256] : 0.f;
    if (j < H_) { hS[j] = h1st[b * H_ + j]; cS[j] = c1st[b * H_ + j]; }
    __syncthreads();

    const float* xgb = xg1 + (size_t)b * TC * G4;
    float* outb = out + (size_t)b * T_ * V_;

    float xv_next = xgb[j];
    for (int t = 0; t < TC; ++t) {
        const float xv = xv_next;
        if (t + 1 < TC) xv_next = xgb[(size_t)(t + 1) * G4 + j];

        // gates for step t (reads hS = h1_{t-1})
        float a0 = 0.f, a1 = 0.f, a2 = 0.f, a3 = 0.f;
        const float4* hv4 = reinterpret_cast<const float4*>(hS);
#pragma unroll
        for (int k4 = 0; k4 < H_ / 4; ++k4) {
            const float4 hv = hv4[k4];
            a0 = fmaf(hv.x, w[4 * k4 + 0], a0);
            a1 = fmaf(hv.y, w[4 * k4 + 1], a1);
            a2 = fmaf(hv.z, w[4 * k4 + 2], a2);
            a3 = fmaf(hv.w, w[4 * k4 + 3], a3);
        }
        // y-partials for h1_{t-1} (same hS, read-only here)
        if (t > 0 && j < V_ * 8) {
            const int v = j >> 3, kk = j & 7;
            const float4* wv = reinterpret_cast<const float4*>(&whyT[v * 132 + kk * 16]);
            const float4* hp = reinterpret_cast<const float4*>(&hS[kk * 16]);
            float p = 0.f;
#pragma unroll
            for (int q = 0; q < 4; ++q) {
                const float4 a = wv[q], h = hp[q];
                p += a.x * h.x + a.y * h.y + a.z * h.z + a.w * h.w;
            }
            pb[v][kk] = p;
        }
        gS[j] = ((a0 + a1) + (a2 + a3)) + xv;
        __syncthreads();

        if (j < H_) {
            const float f  = sigf(gS[j]);
            const float i_ = sigf(gS[H_ + j]);
            const float g  = tanhf(gS[2 * H_ + j]);
            const float o  = sigf(gS[3 * H_ + j]);
            const float c  = f * cS[j] + i_ * g;
            cS[j] = c;
            hS[j] = tanhf(c) * o;
        } else if (t > 0 && j >= 256 && j < 256 + V_) {
            const float4* pq = reinterpret_cast<const float4*>(&pb[j - 256][0]);
            const float4 u = pq[0], v4 = pq[1];
            outb[(size_t)(t0 + t - 1) * V_ + (j - 256)] =
                byv + ((u.x + u.y) + (u.z + u.w)) + ((v4.x + v4.y) + (v4.z + v4.w));
        }
        __syncthreads();
    }

    // flush y for last step of chunk (hS = h1_{TC-1})
    if (j < V_ * 8) {
        const int v = j >> 3, kk = j & 7;
        const float4* wv = reinterpret_cast<const float4*>(&whyT[v * 132 + kk * 16]);
        const float4* hp = reinterpret_cast<const float4*>(&hS[kk * 16]);
        float p = 0.f;
#pragma unroll
        for (int q = 0; q < 4; ++q) {
            const float4 a = wv[q], h = hp[q];
            p += a.x * h.x + a.y * h.y + a.z * h.z + a.w * h.w;
        }
        pb[v][kk] = p;
    }
    __syncthreads();
    if (j >= 256 && j < 256 + V_) {
        const float4* pq = reinterpret_cast<const float4*>(&pb[j - 256][0]);
        const float4 u = pq[0], v4 = pq[1];
        outb[(size_t)(t0 + TC - 1) * V_ + (j - 256)] =
            byv + ((u.x + u.y) + (u.z + u.w)) + ((v4.x + v4.y) + (v4.z + v4.w));
    }
    if (j < H_) { h1st[b * H_ + j] = hS[j]; c1st[b * H_ + j] = cS[j]; }
}

// ---------------- fallback: round-1 streaming kernel ----------------
__global__ __launch_bounds__(G4, 1)
void lstm_persist(const int* __restrict__ x,
                  const float* __restrict__ table0,
                  const float* __restrict__ wh0,
                  const float* __restrict__ wx1,
                  const float* __restrict__ wh1,
                  const float* __restrict__ b1,
                  const float* __restrict__ why,
                  const float* __restrict__ by,
                  float* __restrict__ out)
{
    const int j  = threadIdx.x;
    const int bb = blockIdx.x * 2;

    __shared__ float h0s[2][H_], c0s[2][H_], h1s[2][H_], c1s[2][H_];
    __shared__ float hcat[2][2 * H_];
    __shared__ float g0s[2][G4], g1s[2][G4];
    __shared__ float whyS[H_ * V_];
    __shared__ float b1S[G4];
    __shared__ float byS[V_];
    __shared__ float pb[2][V_][8];

    for (int i = j; i < H_ * V_; i += G4) whyS[i] = why[i];
    b1S[j] = b1[j];
    if (j < V_) byS[j] = by[j];
    if (j < H_) {
        h0s[0][j] = 0.f; h0s[1][j] = 0.f; c0s[0][j] = 0.f; c0s[1][j] = 0.f;
        h1s[0][j] = 0.f; h1s[1][j] = 0.f; c1s[0][j] = 0.f; c1s[1][j] = 0.f;
    }
    __syncthreads();

    const int* xA = x + (size_t)(bb + 0) * T_;
    const int* xB = x + (size_t)(bb + 1) * T_;
    float* outA = out + (size_t)(bb + 0) * T_ * V_;
    float* outB = out + (size_t)(bb + 1) * T_ * V_;

    for (int t = 0; t < T_; ++t) {
        const int ia = xA[t];
        const int ib = xB[t];
        float aA = table0[ia * G4 + j];
        float aB = table0[ib * G4 + j];
#pragma unroll 8
        for (int k = 0; k < H_; ++k) {
            const float w = wh0[k * G4 + j];
            aA += h0s[0][k] * w;
            aB += h0s[1][k] * w;
        }
        g0s[0][j] = aA; g0s[1][j] = aB;
        __syncthreads();

        if (j < 2 * H_) {
            const int gi = j >> 7, r = j & (H_ - 1);
            const float f  = sigf(g0s[gi][r]);
            const float i_ = sigf(g0s[gi][H_ + r]);
            const float g  = tanhf(g0s[gi][2 * H_ + r]);
            const float o  = sigf(g0s[gi][3 * H_ + r]);
            const float c  = f * c0s[gi][r] + i_ * g;
            c0s[gi][r] = c;
            const float h = tanhf(c) * o;
            h0s[gi][r] = h;
            hcat[gi][r] = h;
            hcat[gi][H_ + r] = h1s[gi][r];
        }
        __syncthreads();

        float bA = b1S[j];
        float bB = bA;
#pragma unroll 8
        for (int k = 0; k < H_; ++k) {
            const float w = wx1[k * G4 + j];
            bA += hcat[0][k] * w;
            bB += hcat[1][k] * w;
        }
#pragma unroll 8
        for (int k = 0; k < H_; ++k) {
            const float w = wh1[k * G4 + j];
            bA += hcat[0][H_ + k] * w;
            bB += hcat[1][H_ + k] * w;
        }
        g1s[0][j] = bA; g1s[1][j] = bB;
        __syncthreads();

        if (j < 2 * H_) {
            const int gi = j >> 7, r = j & (H_ - 1);
            const float f  = sigf(g1s[gi][r]);
            const float i_ = sigf(g1s[gi][H_ + r]);
            const float g  = tanhf(g1s[gi][2 * H_ + r]);
            const float o  = sigf(g1s[gi][3 * H_ + r]);
            const float c  = f * c1s[gi][r] + i_ * g;
            c1s[gi][r] = c;
            h1s[gi][r] = tanhf(c) * o;
        }
        __syncthreads();

        if (j < 2 * V_ * 8) {
            int q = j;
            const int gi = (q >= V_ * 8) ? 1 : 0;
            q -= gi * V_ * 8;
            const int v = q >> 3, kk = q & 7;
            float p = 0.f;
#pragma unroll
            for (int k = kk * 16; k < kk * 16 + 16; ++k)
                p += h1s[gi][k] * whyS[k * V_ + v];
            pb[gi][v][kk] = p;
        }
        __syncthreads();

        if (j < 2 * V_) {
            const int gi = (j >= V_) ? 1 : 0;
            const int v  = j - gi * V_;
            float s = byS[v];
#pragma unroll
            for (int q = 0; q < 8; ++q) s += pb[gi][v][q];
            (gi ? outB : outA)[t * V_ + v] = s;
        }
        __syncthreads();
    }
}

// ---------------- host ----------------
extern "C" void kernel_launch(void* const* d_in, const int* in_sizes, int n_in,
                              void* d_out, int out_size, void* d_ws, size_t ws_size,
                              hipStream_t stream)
{
    const int*   x   = (const int*)  d_in[0];
    const float* emb = (const float*)d_in[1];
    const float* wx0 = (const float*)d_in[2];
    const float* wh0 = (const float*)d_in[3];
    const float* b0  = (const float*)d_in[4];
    const float* wx1 = (const float*)d_in[5];
    const float* wh1 = (const float*)d_in[6];
    const float* b1  = (const float*)d_in[7];
    const float* why = (const float*)d_in[8];
    const float* by  = (const float*)d_in[9];
    float* out = (float*)d_out;
    float* wsf = (float*)d_ws;

    const size_t tabF   = (size_t)V_ * G4;       // 13824 floats
    const size_t stateF = (size_t)4 * B_ * H_;   // 131072 floats

    int TC = 0;
    for (int tc = T_; tc >= 32; tc >>= 1) {
        const size_t need = (tabF + stateF + (size_t)B_ * tc * (H_ + G4)) * 4;
        if (need <= ws_size) { TC = tc; break; }
    }

    float* table0 = wsf;
    build_table0<<<dim3(V_), dim3(G4), 0, stream>>>(emb, wx0, b0, table0);

    if (TC == 0) {
        // ws too small for phases: round-1 streaming fallback
        lstm_persist<<<dim3(B_ / 2), dim3(G4), 0, stream>>>(
            x, table0, wh0, wx1, wh1, b1, why, by, out);
        return;
    }

    float* h0st   = wsf + tabF;
    float* c0st   = h0st + (size_t)B_ * H_;
    float* h1st   = c0st + (size_t)B_ * H_;
    float* c1st   = h1st + (size_t)B_ * H_;
    float* h0buf  = c1st + (size_t)B_ * H_;
    float* xg1buf = h0buf + (size_t)B_ * TC * H_;

    hipMemsetAsync(h0st, 0, stateF * sizeof(float), stream);

    const int NC = T_ / TC;
    for (int c = 0; c < NC; ++c) {
        const int t0 = c * TC;
        lstm_l0_chunk<<<dim3(B_), dim3(G4), 0, stream>>>(
            x, table0, wh0, h0st, c0st, h0buf, t0, TC);
        gemm_xg1<<<dim3(4 * TC), dim3(G4), 0, stream>>>(
            h0buf, wx1, b1, xg1buf);
        lstm_l1_chunk<<<dim3(B_), dim3(G4), 0, stream>>>(
            xg1buf, wh1, why, by, h1st, c1st, out, t0, TC);
    }
}

// Round 3
// 6778.767 us; speedup vs baseline: 1.5618x; 1.0015x over previous
//
#include <hip/hip_runtime.h>

// MultiLayerLSTM: B=256, T=1024, V=27, E=64, H=128 (4H=512)
// Round 3: fix register-spill catastrophe from round 2.
//   - lstm_l0/l1: __launch_bounds__(512,1) -> 256-VGPR budget, w[128] stays
//     register-resident (round 2's (512,2) capped at 128 VGPRs and spilled
//     ~1 GB/dispatch of scratch traffic, visible as WRITE_SIZE=1.06GB).
//   - gemm_xg1: (512,4)->(512,2): 128-VGPR budget for the 64-reg accumulator.
// Structure unchanged: P0 table, P1 l0-recurrence (wh0 in VGPRs),
// P2 GEMM xg1 = h0@wx1+b1, P3 l1-recurrence (wh1 in VGPRs) + fused y-proj.

#define B_  256
#define T_  1024
#define V_  27
#define E_  64
#define H_  128
#define G4  512   // 4*H

__device__ __forceinline__ float sigf(float x) { return 1.0f / (1.0f + expf(-x)); }

// ---------------- P0: token table ----------------
__global__ __launch_bounds__(G4)
void build_table0(const float* __restrict__ emb,
                  const float* __restrict__ wx0,
                  const float* __restrict__ b0,
                  float* __restrict__ table0)
{
    const int v = blockIdx.x;        // 0..26
    const int j = threadIdx.x;       // 0..511
    __shared__ float e[E_];
    if (j < E_) e[j] = emb[v * E_ + j];
    __syncthreads();
    float s = b0[j];
#pragma unroll 8
    for (int k = 0; k < E_; ++k) s += e[k] * wx0[k * G4 + j];
    table0[v * G4 + j] = s;
}

// ---------------- P1: layer-0 recurrence (wh0 in registers) ----------------
__global__ __launch_bounds__(G4, 1)
void lstm_l0_chunk(const int* __restrict__ x,
                   const float* __restrict__ table0,
                   const float* __restrict__ wh0,
                   float* __restrict__ h0st, float* __restrict__ c0st,
                   float* __restrict__ h0buf,
                   int t0, int TC)
{
    const int j = threadIdx.x;
    const int b = blockIdx.x;

    __shared__ __align__(16) float hS[H_];
    __shared__ float cS[H_];
    __shared__ float gS[G4];
    __shared__ float tabS[V_ * G4];   // 55296 B

    float w[H_];
#pragma unroll
    for (int k = 0; k < H_; ++k) w[k] = wh0[k * G4 + j];
    for (int e = j; e < V_ * G4; e += G4) tabS[e] = table0[e];
    if (j < H_) { hS[j] = h0st[b * H_ + j]; cS[j] = c0st[b * H_ + j]; }
    __syncthreads();

    const int* xb = x + (size_t)b * T_ + t0;
    float* hob = h0buf + (size_t)b * TC * H_;

    int idx_next = xb[0];
    for (int t = 0; t < TC; ++t) {
        const int idx = idx_next;
        if (t + 1 < TC) idx_next = xb[t + 1];

        float a0 = 0.f, a1 = 0.f, a2 = 0.f, a3 = 0.f;
        const float tv = tabS[idx * G4 + j];
        const float4* hv4 = reinterpret_cast<const float4*>(hS);
#pragma unroll
        for (int k4 = 0; k4 < H_ / 4; ++k4) {
            const float4 hv = hv4[k4];
            a0 = fmaf(hv.x, w[4 * k4 + 0], a0);
            a1 = fmaf(hv.y, w[4 * k4 + 1], a1);
            a2 = fmaf(hv.z, w[4 * k4 + 2], a2);
            a3 = fmaf(hv.w, w[4 * k4 + 3], a3);
        }
        gS[j] = ((a0 + a1) + (a2 + a3)) + tv;
        __syncthreads();

        if (j < H_) {
            const float f  = sigf(gS[j]);
            const float i_ = sigf(gS[H_ + j]);
            const float g  = tanhf(gS[2 * H_ + j]);
            const float o  = sigf(gS[3 * H_ + j]);
            const float c  = f * cS[j] + i_ * g;
            cS[j] = c;
            const float h = tanhf(c) * o;
            hS[j] = h;
            hob[(size_t)t * H_ + j] = h;
        }
        __syncthreads();
    }
    if (j < H_) { h0st[b * H_ + j] = hS[j]; c0st[b * H_ + j] = cS[j]; }
}

// ---------------- P2: xg1 = h0 @ wx1 + b1 ----------------
// block: 64 rows x 512 cols; thread: 16 rows x 4 cols (acc[4][16])
__global__ __launch_bounds__(G4, 2)
void gemm_xg1(const float* __restrict__ h0buf,
              const float* __restrict__ wx1,
              const float* __restrict__ b1,
              float* __restrict__ xg1)
{
    const int j  = threadIdx.x;
    const size_t m0 = (size_t)blockIdx.x * 64;
    const int c  = j & 127;          // cols c, c+128, c+256, c+384
    const int rg = j >> 7;           // rows rg*16 .. rg*16+15

    __shared__ __align__(16) float aT[64 * 132];   // row-major [r][k], pad 132

    // load A tile 64x128 (float4 coalesced)
#pragma unroll
    for (int i = 0; i < 4; ++i) {
        const int e  = i * G4 + j;       // float4 index 0..2047
        const int r  = e >> 5;           // 32 float4 per row
        const int k4 = e & 31;
        const float4 v = *reinterpret_cast<const float4*>(&h0buf[(m0 + r) * H_ + k4 * 4]);
        *reinterpret_cast<float4*>(&aT[r * 132 + k4 * 4]) = v;
    }
    __syncthreads();

    float acc[4][16];
#pragma unroll
    for (int cc = 0; cc < 4; ++cc)
#pragma unroll
        for (int rr = 0; rr < 16; ++rr) acc[cc][rr] = 0.f;

    for (int k4 = 0; k4 < 32; ++k4) {
        float bv[4][4];   // [kk][cc]
#pragma unroll
        for (int kk = 0; kk < 4; ++kk)
#pragma unroll
            for (int cc = 0; cc < 4; ++cc)
                bv[kk][cc] = wx1[(size_t)(k4 * 4 + kk) * G4 + cc * 128 + c];
#pragma unroll
        for (int rr = 0; rr < 16; ++rr) {
            const float4 av = *reinterpret_cast<const float4*>(&aT[(rg * 16 + rr) * 132 + k4 * 4]);
#pragma unroll
            for (int cc = 0; cc < 4; ++cc) {
                acc[cc][rr] = fmaf(av.x, bv[0][cc], acc[cc][rr]);
                acc[cc][rr] = fmaf(av.y, bv[1][cc], acc[cc][rr]);
                acc[cc][rr] = fmaf(av.z, bv[2][cc], acc[cc][rr]);
                acc[cc][rr] = fmaf(av.w, bv[3][cc], acc[cc][rr]);
            }
        }
    }

    float b1v[4];
#pragma unroll
    for (int cc = 0; cc < 4; ++cc) b1v[cc] = b1[cc * 128 + c];
#pragma unroll
    for (int rr = 0; rr < 16; ++rr) {
        const size_t row = m0 + rg * 16 + rr;
#pragma unroll
        for (int cc = 0; cc < 4; ++cc)
            xg1[row * G4 + cc * 128 + c] = acc[cc][rr] + b1v[cc];
    }
}

// ---------------- P3: layer-1 recurrence (wh1 in registers) + y ----------------
__global__ __launch_bounds__(G4, 1)
void lstm_l1_chunk(const float* __restrict__ xg1,
                   const float* __restrict__ wh1,
                   const float* __restrict__ why,
                   const float* __restrict__ by,
                   float* __restrict__ h1st, float* __restrict__ c1st,
                   float* __restrict__ out,
                   int t0, int TC)
{
    const int j = threadIdx.x;
    const int b = blockIdx.x;

    __shared__ __align__(16) float hS[H_];
    __shared__ float cS[H_];
    __shared__ float gS[G4];
    __shared__ __align__(16) float whyT[V_ * 132];  // [v][k] pad 132
    __shared__ __align__(16) float pb[V_][8];

    float w[H_];
#pragma unroll
    for (int k = 0; k < H_; ++k) w[k] = wh1[k * G4 + j];
    for (int e = j; e < V_ * H_; e += G4) whyT[(e % V_) * 132 + e / V_] = why[e];
    const float byv = (j >= 256 && j < 256 + V_) ? by[j - 256] : 0.f;
    if (j < H_) { hS[j] = h1st[b * H_ + j]; cS[j] = c1st[b * H_ + j]; }
    __syncthreads();

    const float* xgb = xg1 + (size_t)b * TC * G4;
    float* outb = out + (size_t)b * T_ * V_;

    float xv_next = xgb[j];
    for (int t = 0; t < TC; ++t) {
        const float xv = xv_next;
        if (t + 1 < TC) xv_next = xgb[(size_t)(t + 1) * G4 + j];

        // gates for step t (reads hS = h1_{t-1})
        float a0 = 0.f, a1 = 0.f, a2 = 0.f, a3 = 0.f;
        const float4* hv4 = reinterpret_cast<const float4*>(hS);
#pragma unroll
        for (int k4 = 0; k4 < H_ / 4; ++k4) {
            const float4 hv = hv4[k4];
            a0 = fmaf(hv.x, w[4 * k4 + 0], a0);
            a1 = fmaf(hv.y, w[4 * k4 + 1], a1);
            a2 = fmaf(hv.z, w[4 * k4 + 2], a2);
            a3 = fmaf(hv.w, w[4 * k4 + 3], a3);
        }
        // y-partials for h1_{t-1} (same hS, read-only here)
        if (t > 0 && j < V_ * 8) {
            const int v = j >> 3, kk = j & 7;
            const float4* wv = reinterpret_cast<const float4*>(&whyT[v * 132 + kk * 16]);
            const float4* hp = reinterpret_cast<const float4*>(&hS[kk * 16]);
            float p = 0.f;
#pragma unroll
            for (int q = 0; q < 4; ++q) {
                const float4 a = wv[q], h = hp[q];
                p += a.x * h.x + a.y * h.y + a.z * h.z + a.w * h.w;
            }
            pb[v][kk] = p;
        }
        gS[j] = ((a0 + a1) + (a2 + a3)) + xv;
        __syncthreads();

        if (j < H_) {
            const float f  = sigf(gS[j]);
            const float i_ = sigf(gS[H_ + j]);
            const float g  = tanhf(gS[2 * H_ + j]);
            const float o  = sigf(gS[3 * H_ + j]);
            const float c  = f * cS[j] + i_ * g;
            cS[j] = c;
            hS[j] = tanhf(c) * o;
        } else if (t > 0 && j >= 256 && j < 256 + V_) {
            const float4* pq = reinterpret_cast<const float4*>(&pb[j - 256][0]);
            const float4 u = pq[0], v4 = pq[1];
            outb[(size_t)(t0 + t - 1) * V_ + (j - 256)] =
                byv + ((u.x + u.y) + (u.z + u.w)) + ((v4.x + v4.y) + (v4.z + v4.w));
        }
        __syncthreads();
    }

    // flush y for last step of chunk (hS = h1_{TC-1})
    if (j < V_ * 8) {
        const int v = j >> 3, kk = j & 7;
        const float4* wv = reinterpret_cast<const float4*>(&whyT[v * 132 + kk * 16]);
        const float4* hp = reinterpret_cast<const float4*>(&hS[kk * 16]);
        float p = 0.f;
#pragma unroll
        for (int q = 0; q < 4; ++q) {
            const float4 a = wv[q], h = hp[q];
            p += a.x * h.x + a.y * h.y + a.z * h.z + a.w * h.w;
        }
        pb[v][kk] = p;
    }
    __syncthreads();
    if (j >= 256 && j < 256 + V_) {
        const float4* pq = reinterpret_cast<const float4*>(&pb[j - 256][0]);
        const float4 u = pq[0], v4 = pq[1];
        outb[(size_t)(t0 + TC - 1) * V_ + (j - 256)] =
            byv + ((u.x + u.y) + (u.z + u.w)) + ((v4.x + v4.y) + (v4.z + v4.w));
    }
    if (j < H_) { h1st[b * H_ + j] = hS[j]; c1st[b * H_ + j] = cS[j]; }
}

// ---------------- fallback: round-1 streaming kernel ----------------
__global__ __launch_bounds__(G4, 1)
void lstm_persist(const int* __restrict__ x,
                  const float* __restrict__ table0,
                  const float* __restrict__ wh0,
                  const float* __restrict__ wx1,
                  const float* __restrict__ wh1,
                  const float* __restrict__ b1,
                  const float* __restrict__ why,
                  const float* __restrict__ by,
                  float* __restrict__ out)
{
    const int j  = threadIdx.x;
    const int bb = blockIdx.x * 2;

    __shared__ float h0s[2][H_], c0s[2][H_], h1s[2][H_], c1s[2][H_];
    __shared__ float hcat[2][2 * H_];
    __shared__ float g0s[2][G4], g1s[2][G4];
    __shared__ float whyS[H_ * V_];
    __shared__ float b1S[G4];
    __shared__ float byS[V_];
    __shared__ float pb[2][V_][8];

    for (int i = j; i < H_ * V_; i += G4) whyS[i] = why[i];
    b1S[j] = b1[j];
    if (j < V_) byS[j] = by[j];
    if (j < H_) {
        h0s[0][j] = 0.f; h0s[1][j] = 0.f; c0s[0][j] = 0.f; c0s[1][j] = 0.f;
        h1s[0][j] = 0.f; h1s[1][j] = 0.f; c1s[0][j] = 0.f; c1s[1][j] = 0.f;
    }
    __syncthreads();

    const int* xA = x + (size_t)(bb + 0) * T_;
    const int* xB = x + (size_t)(bb + 1) * T_;
    float* outA = out + (size_t)(bb + 0) * T_ * V_;
    float* outB = out + (size_t)(bb + 1) * T_ * V_;

    for (int t = 0; t < T_; ++t) {
        const int ia = xA[t];
        const int ib = xB[t];
        float aA = table0[ia * G4 + j];
        float aB = table0[ib * G4 + j];
#pragma unroll 8
        for (int k = 0; k < H_; ++k) {
            const float w = wh0[k * G4 + j];
            aA += h0s[0][k] * w;
            aB += h0s[1][k] * w;
        }
        g0s[0][j] = aA; g0s[1][j] = aB;
        __syncthreads();

        if (j < 2 * H_) {
            const int gi = j >> 7, r = j & (H_ - 1);
            const float f  = sigf(g0s[gi][r]);
            const float i_ = sigf(g0s[gi][H_ + r]);
            const float g  = tanhf(g0s[gi][2 * H_ + r]);
            const float o  = sigf(g0s[gi][3 * H_ + r]);
            const float c  = f * c0s[gi][r] + i_ * g;
            c0s[gi][r] = c;
            const float h = tanhf(c) * o;
            h0s[gi][r] = h;
            hcat[gi][r] = h;
            hcat[gi][H_ + r] = h1s[gi][r];
        }
        __syncthreads();

        float bA = b1S[j];
        float bB = bA;
#pragma unroll 8
        for (int k = 0; k < H_; ++k) {
            const float w = wx1[k * G4 + j];
            bA += hcat[0][k] * w;
            bB += hcat[1][k] * w;
        }
#pragma unroll 8
        for (int k = 0; k < H_; ++k) {
            const float w = wh1[k * G4 + j];
            bA += hcat[0][H_ + k] * w;
            bB += hcat[1][H_ + k] * w;
        }
        g1s[0][j] = bA; g1s[1][j] = bB;
        __syncthreads();

        if (j < 2 * H_) {
            const int gi = j >> 7, r = j & (H_ - 1);
            const float f  = sigf(g1s[gi][r]);
            const float i_ = sigf(g1s[gi][H_ + r]);
            const float g  = tanhf(g1s[gi][2 * H_ + r]);
            const float o  = sigf(g1s[gi][3 * H_ + r]);
            const float c  = f * c1s[gi][r] + i_ * g;
            c1s[gi][r] = c;
            h1s[gi][r] = tanhf(c) * o;
        }
        __syncthreads();

        if (j < 2 * V_ * 8) {
            int q = j;
            const int gi = (q >= V_ * 8) ? 1 : 0;
            q -= gi * V_ * 8;
            const int v = q >> 3, kk = q & 7;
            float p = 0.f;
#pragma unroll
            for (int k = kk * 16; k < kk * 16 + 16; ++k)
                p += h1s[gi][k] * whyS[k * V_ + v];
            pb[gi][v][kk] = p;
        }
        __syncthreads();

        if (j < 2 * V_) {
            const int gi = (j >= V_) ? 1 : 0;
            const int v  = j - gi * V_;
            float s = byS[v];
#pragma unroll
            for (int q = 0; q < 8; ++q) s += pb[gi][v][q];
            (gi ? outB : outA)[t * V_ + v] = s;
        }
        __syncthreads();
    }
}

// ---------------- host ----------------
extern "C" void kernel_launch(void* const* d_in, const int* in_sizes, int n_in,
                              void* d_out, int out_size, void* d_ws, size_t ws_size,
                              hipStream_t stream)
{
    const int*   x   = (const int*)  d_in[0];
    const float* emb = (const float*)d_in[1];
    const float* wx0 = (const float*)d_in[2];
    const float* wh0 = (const float*)d_in[3];
    const float* b0  = (const float*)d_in[4];
    const float* wx1 = (const float*)d_in[5];
    const float* wh1 = (const float*)d_in[6];
    const float* b1  = (const float*)d_in[7];
    const float* why = (const float*)d_in[8];
    const float* by  = (const float*)d_in[9];
    float* out = (float*)d_out;
    float* wsf = (float*)d_ws;

    const size_t tabF   = (size_t)V_ * G4;       // 13824 floats
    const size_t stateF = (size_t)4 * B_ * H_;   // 131072 floats

    int TC = 0;
    for (int tc = T_; tc >= 32; tc >>= 1) {
        const size_t need = (tabF + stateF + (size_t)B_ * tc * (H_ + G4)) * 4;
        if (need <= ws_size) { TC = tc; break; }
    }

    float* table0 = wsf;
    build_table0<<<dim3(V_), dim3(G4), 0, stream>>>(emb, wx0, b0, table0);

    if (TC == 0) {
        // ws too small for phases: round-1 streaming fallback
        lstm_persist<<<dim3(B_ / 2), dim3(G4), 0, stream>>>(
            x, table0, wh0, wx1, wh1, b1, why, by, out);
        return;
    }

    float* h0st   = wsf + tabF;
    float* c0st   = h0st + (size_t)B_ * H_;
    float* h1st   = c0st + (size_t)B_ * H_;
    float* c1st   = h1st + (size_t)B_ * H_;
    float* h0buf  = c1st + (size_t)B_ * H_;
    float* xg1buf = h0buf + (size_t)B_ * TC * H_;

    hipMemsetAsync(h0st, 0, stateF * sizeof(float), stream);

    const int NC = T_ / TC;
    for (int c = 0; c < NC; ++c) {
        const int t0 = c * TC;
        lstm_l0_chunk<<<dim3(B_), dim3(G4), 0, stream>>>(
            x, table0, wh0, h0st, c0st, h0buf, t0, TC);
        gemm_xg1<<<dim3(4 * TC), dim3(G4), 0, stream>>>(
            h0buf, wx1, b1, xg1buf);
        lstm_l1_chunk<<<dim3(B_), dim3(G4), 0, stream>>>(
            xg1buf, wh1, why, by, h1st, c1st, out, t0, TC);
    }
}

// Round 4
// 5615.842 us; speedup vs baseline: 1.8852x; 1.2071x over previous
//
#include <hip/hip_runtime.h>

// MultiLayerLSTM: B=256, T=1024, V=27, E=64, H=128 (4H=512)
// Round 4: kill the scratch-resident weight array (guide rule #20).
//   Rounds 2/3 declared `float w[128]` filled in a loop -> runtime index at
//   SROA time -> alloca stays in scratch -> 1.06 GB/dispatch scratch writes
//   (WRITE_SIZE), VGPR_Count=128 (weights never in registers), dur unchanged
//   by launch_bounds. Fix: 128 NAMED scalars via REPEAT32 macro; every access
//   is a frontend-literal constant -> guaranteed register promotion.
// Structure unchanged: P0 table, P1 l0-recurrence (wh0 in VGPRs),
// P2 GEMM xg1 = h0@wx1+b1, P3 l1-recurrence (wh1 in VGPRs) + fused y-proj.

#define B_  256
#define T_  1024
#define V_  27
#define E_  64
#define H_  128
#define G4  512   // 4*H

#define REPEAT32(M) M(0) M(1) M(2) M(3) M(4) M(5) M(6) M(7) \
                    M(8) M(9) M(10) M(11) M(12) M(13) M(14) M(15) \
                    M(16) M(17) M(18) M(19) M(20) M(21) M(22) M(23) \
                    M(24) M(25) M(26) M(27) M(28) M(29) M(30) M(31)

// declare 4 named weight scalars per K (k = 4K..4K+3)
#define DECLW(K) float w##K##x, w##K##y, w##K##z, w##K##w;
// load column j of rows 4K..4K+3 of a [128][512] row-major matrix
#define LOADW(K) w##K##x = wmat[(size_t)((K)*4+0)*G4 + j]; \
                 w##K##y = wmat[(size_t)((K)*4+1)*G4 + j]; \
                 w##K##z = wmat[(size_t)((K)*4+2)*G4 + j]; \
                 w##K##w = wmat[(size_t)((K)*4+3)*G4 + j];
// fused multiply-add against the broadcast h float4 #K
#define FMA4(K) { const float4 hv = hv4[K]; \
                  a0 = fmaf(hv.x, w##K##x, a0); \
                  a1 = fmaf(hv.y, w##K##y, a1); \
                  a2 = fmaf(hv.z, w##K##z, a2); \
                  a3 = fmaf(hv.w, w##K##w, a3); }

__device__ __forceinline__ float sigf(float x) { return 1.0f / (1.0f + expf(-x)); }

// ---------------- P0: token table ----------------
__global__ __launch_bounds__(G4)
void build_table0(const float* __restrict__ emb,
                  const float* __restrict__ wx0,
                  const float* __restrict__ b0,
                  float* __restrict__ table0)
{
    const int v = blockIdx.x;        // 0..26
    const int j = threadIdx.x;       // 0..511
    __shared__ float e[E_];
    if (j < E_) e[j] = emb[v * E_ + j];
    __syncthreads();
    float s = b0[j];
#pragma unroll 8
    for (int k = 0; k < E_; ++k) s += e[k] * wx0[k * G4 + j];
    table0[v * G4 + j] = s;
}

// ---------------- P1: layer-0 recurrence (wh0 in named registers) ----------------
__global__ __launch_bounds__(G4, 1)
void lstm_l0_chunk(const int* __restrict__ x,
                   const float* __restrict__ table0,
                   const float* __restrict__ wh0,
                   float* __restrict__ h0st, float* __restrict__ c0st,
                   float* __restrict__ h0buf,
                   int t0, int TC)
{
    const int j = threadIdx.x;
    const int b = blockIdx.x;

    __shared__ __align__(16) float hS[H_];
    __shared__ float cS[H_];
    __shared__ float gS[G4];
    __shared__ float tabS[V_ * G4];   // 55296 B

    const float* wmat = wh0;
    REPEAT32(DECLW)
    REPEAT32(LOADW)
    for (int e = j; e < V_ * G4; e += G4) tabS[e] = table0[e];
    if (j < H_) { hS[j] = h0st[b * H_ + j]; cS[j] = c0st[b * H_ + j]; }
    __syncthreads();

    const int* xb = x + (size_t)b * T_ + t0;
    float* hob = h0buf + (size_t)b * TC * H_;

    int idx_next = xb[0];
    for (int t = 0; t < TC; ++t) {
        const int idx = idx_next;
        if (t + 1 < TC) idx_next = xb[t + 1];

        float a0 = 0.f, a1 = 0.f, a2 = 0.f, a3 = 0.f;
        const float tv = tabS[idx * G4 + j];
        const float4* hv4 = reinterpret_cast<const float4*>(hS);
        REPEAT32(FMA4)
        gS[j] = ((a0 + a1) + (a2 + a3)) + tv;
        __syncthreads();

        if (j < H_) {
            const float f  = sigf(gS[j]);
            const float i_ = sigf(gS[H_ + j]);
            const float g  = tanhf(gS[2 * H_ + j]);
            const float o  = sigf(gS[3 * H_ + j]);
            const float c  = f * cS[j] + i_ * g;
            cS[j] = c;
            const float h = tanhf(c) * o;
            hS[j] = h;
            hob[(size_t)t * H_ + j] = h;
        }
        __syncthreads();
    }
    if (j < H_) { h0st[b * H_ + j] = hS[j]; c0st[b * H_ + j] = cS[j]; }
}

// ---------------- P2: xg1 = h0 @ wx1 + b1 ----------------
// block: 64 rows x 512 cols; thread: 16 rows x 4 cols (acc[4][16])
__global__ __launch_bounds__(G4, 2)
void gemm_xg1(const float* __restrict__ h0buf,
              const float* __restrict__ wx1,
              const float* __restrict__ b1,
              float* __restrict__ xg1)
{
    const int j  = threadIdx.x;
    const size_t m0 = (size_t)blockIdx.x * 64;
    const int c  = j & 127;          // cols c, c+128, c+256, c+384
    const int rg = j >> 7;           // rows rg*16 .. rg*16+15

    __shared__ __align__(16) float aT[64 * 132];   // row-major [r][k], pad 132

    // load A tile 64x128 (float4 coalesced)
#pragma unroll
    for (int i = 0; i < 4; ++i) {
        const int e  = i * G4 + j;       // float4 index 0..2047
        const int r  = e >> 5;           // 32 float4 per row
        const int k4 = e & 31;
        const float4 v = *reinterpret_cast<const float4*>(&h0buf[(m0 + r) * H_ + k4 * 4]);
        *reinterpret_cast<float4*>(&aT[r * 132 + k4 * 4]) = v;
    }
    __syncthreads();

    float acc[4][16];
#pragma unroll
    for (int cc = 0; cc < 4; ++cc)
#pragma unroll
        for (int rr = 0; rr < 16; ++rr) acc[cc][rr] = 0.f;

    for (int k4 = 0; k4 < 32; ++k4) {
        float bv[4][4];   // [kk][cc]
#pragma unroll
        for (int kk = 0; kk < 4; ++kk)
#pragma unroll
            for (int cc = 0; cc < 4; ++cc)
                bv[kk][cc] = wx1[(size_t)(k4 * 4 + kk) * G4 + cc * 128 + c];
#pragma unroll
        for (int rr = 0; rr < 16; ++rr) {
            const float4 av = *reinterpret_cast<const float4*>(&aT[(rg * 16 + rr) * 132 + k4 * 4]);
#pragma unroll
            for (int cc = 0; cc < 4; ++cc) {
                acc[cc][rr] = fmaf(av.x, bv[0][cc], acc[cc][rr]);
                acc[cc][rr] = fmaf(av.y, bv[1][cc], acc[cc][rr]);
                acc[cc][rr] = fmaf(av.z, bv[2][cc], acc[cc][rr]);
                acc[cc][rr] = fmaf(av.w, bv[3][cc], acc[cc][rr]);
            }
        }
    }

    float b1v[4];
#pragma unroll
    for (int cc = 0; cc < 4; ++cc) b1v[cc] = b1[cc * 128 + c];
#pragma unroll
    for (int rr = 0; rr < 16; ++rr) {
        const size_t row = m0 + rg * 16 + rr;
#pragma unroll
        for (int cc = 0; cc < 4; ++cc)
            xg1[row * G4 + cc * 128 + c] = acc[cc][rr] + b1v[cc];
    }
}

// ---------------- P3: layer-1 recurrence (wh1 in named registers) + y ----------------
__global__ __launch_bounds__(G4, 1)
void lstm_l1_chunk(const float* __restrict__ xg1,
                   const float* __restrict__ wh1,
                   const float* __restrict__ why,
                   const float* __restrict__ by,
                   float* __restrict__ h1st, float* __restrict__ c1st,
                   float* __restrict__ out,
                   int t0, int TC)
{
    const int j = threadIdx.x;
    const int b = blockIdx.x;

    __shared__ __align__(16) float hS[H_];
    __shared__ float cS[H_];
    __shared__ float gS[G4];
    __shared__ __align__(16) float whyT[V_ * 132];  // [v][k] pad 132
    __shared__ __align__(16) float pb[V_][8];

    const float* wmat = wh1;
    REPEAT32(DECLW)
    REPEAT32(LOADW)
    for (int e = j; e < V_ * H_; e += G4) whyT[(e % V_) * 132 + e / V_] = why[e];
    const float byv = (j >= 256 && j < 256 + V_) ? by[j - 256] : 0.f;
    if (j < H_) { hS[j] = h1st[b * H_ + j]; cS[j] = c1st[b * H_ + j]; }
    __syncthreads();

    const float* xgb = xg1 + (size_t)b * TC * G4;
    float* outb = out + (size_t)b * T_ * V_;

    float xv_next = xgb[j];
    for (int t = 0; t < TC; ++t) {
        const float xv = xv_next;
        if (t + 1 < TC) xv_next = xgb[(size_t)(t + 1) * G4 + j];

        // gates for step t (reads hS = h1_{t-1})
        float a0 = 0.f, a1 = 0.f, a2 = 0.f, a3 = 0.f;
        const float4* hv4 = reinterpret_cast<const float4*>(hS);
        REPEAT32(FMA4)
        // y-partials for h1_{t-1} (same hS, read-only here)
        if (t > 0 && j < V_ * 8) {
            const int v = j >> 3, kk = j & 7;
            const float4* wv = reinterpret_cast<const float4*>(&whyT[v * 132 + kk * 16]);
            const float4* hp = reinterpret_cast<const float4*>(&hS[kk * 16]);
            float p = 0.f;
#pragma unroll
            for (int q = 0; q < 4; ++q) {
                const float4 a = wv[q], h = hp[q];
                p += a.x * h.x + a.y * h.y + a.z * h.z + a.w * h.w;
            }
            pb[v][kk] = p;
        }
        gS[j] = ((a0 + a1) + (a2 + a3)) + xv;
        __syncthreads();

        if (j < H_) {
            const float f  = sigf(gS[j]);
            const float i_ = sigf(gS[H_ + j]);
            const float g  = tanhf(gS[2 * H_ + j]);
            const float o  = sigf(gS[3 * H_ + j]);
            const float c  = f * cS[j] + i_ * g;
            cS[j] = c;
            hS[j] = tanhf(c) * o;
        } else if (t > 0 && j >= 256 && j < 256 + V_) {
            const float4* pq = reinterpret_cast<const float4*>(&pb[j - 256][0]);
            const float4 u = pq[0], v4 = pq[1];
            outb[(size_t)(t0 + t - 1) * V_ + (j - 256)] =
                byv + ((u.x + u.y) + (u.z + u.w)) + ((v4.x + v4.y) + (v4.z + v4.w));
        }
        __syncthreads();
    }

    // flush y for last step of chunk (hS = h1_{TC-1})
    if (j < V_ * 8) {
        const int v = j >> 3, kk = j & 7;
        const float4* wv = reinterpret_cast<const float4*>(&whyT[v * 132 + kk * 16]);
        const float4* hp = reinterpret_cast<const float4*>(&hS[kk * 16]);
        float p = 0.f;
#pragma unroll
        for (int q = 0; q < 4; ++q) {
            const float4 a = wv[q], h = hp[q];
            p += a.x * h.x + a.y * h.y + a.z * h.z + a.w * h.w;
        }
        pb[v][kk] = p;
    }
    __syncthreads();
    if (j >= 256 && j < 256 + V_) {
        const float4* pq = reinterpret_cast<const float4*>(&pb[j - 256][0]);
        const float4 u = pq[0], v4 = pq[1];
        outb[(size_t)(t0 + TC - 1) * V_ + (j - 256)] =
            byv + ((u.x + u.y) + (u.z + u.w)) + ((v4.x + v4.y) + (v4.z + v4.w));
    }
    if (j < H_) { h1st[b * H_ + j] = hS[j]; c1st[b * H_ + j] = cS[j]; }
}

// ---------------- fallback: round-1 streaming kernel ----------------
__global__ __launch_bounds__(G4, 1)
void lstm_persist(const int* __restrict__ x,
                  const float* __restrict__ table0,
                  const float* __restrict__ wh0,
                  const float* __restrict__ wx1,
                  const float* __restrict__ wh1,
                  const float* __restrict__ b1,
                  const float* __restrict__ why,
                  const float* __restrict__ by,
                  float* __restrict__ out)
{
    const int j  = threadIdx.x;
    const int bb = blockIdx.x * 2;

    __shared__ float h0s[2][H_], c0s[2][H_], h1s[2][H_], c1s[2][H_];
    __shared__ float hcat[2][2 * H_];
    __shared__ float g0s[2][G4], g1s[2][G4];
    __shared__ float whyS[H_ * V_];
    __shared__ float b1S[G4];
    __shared__ float byS[V_];
    __shared__ float pb[2][V_][8];

    for (int i = j; i < H_ * V_; i += G4) whyS[i] = why[i];
    b1S[j] = b1[j];
    if (j < V_) byS[j] = by[j];
    if (j < H_) {
        h0s[0][j] = 0.f; h0s[1][j] = 0.f; c0s[0][j] = 0.f; c0s[1][j] = 0.f;
        h1s[0][j] = 0.f; h1s[1][j] = 0.f; c1s[0][j] = 0.f; c1s[1][j] = 0.f;
    }
    __syncthreads();

    const int* xA = x + (size_t)(bb + 0) * T_;
    const int* xB = x + (size_t)(bb + 1) * T_;
    float* outA = out + (size_t)(bb + 0) * T_ * V_;
    float* outB = out + (size_t)(bb + 1) * T_ * V_;

    for (int t = 0; t < T_; ++t) {
        const int ia = xA[t];
        const int ib = xB[t];
        float aA = table0[ia * G4 + j];
        float aB = table0[ib * G4 + j];
#pragma unroll 8
        for (int k = 0; k < H_; ++k) {
            const float w = wh0[k * G4 + j];
            aA += h0s[0][k] * w;
            aB += h0s[1][k] * w;
        }
        g0s[0][j] = aA; g0s[1][j] = aB;
        __syncthreads();

        if (j < 2 * H_) {
            const int gi = j >> 7, r = j & (H_ - 1);
            const float f  = sigf(g0s[gi][r]);
            const float i_ = sigf(g0s[gi][H_ + r]);
            const float g  = tanhf(g0s[gi][2 * H_ + r]);
            const float o  = sigf(g0s[gi][3 * H_ + r]);
            const float c  = f * c0s[gi][r] + i_ * g;
            c0s[gi][r] = c;
            const float h = tanhf(c) * o;
            h0s[gi][r] = h;
            hcat[gi][r] = h;
            hcat[gi][H_ + r] = h1s[gi][r];
        }
        __syncthreads();

        float bA = b1S[j];
        float bB = bA;
#pragma unroll 8
        for (int k = 0; k < H_; ++k) {
            const float w = wx1[k * G4 + j];
            bA += hcat[0][k] * w;
            bB += hcat[1][k] * w;
        }
#pragma unroll 8
        for (int k = 0; k < H_; ++k) {
            const float w = wh1[k * G4 + j];
            bA += hcat[0][H_ + k] * w;
            bB += hcat[1][H_ + k] * w;
        }
        g1s[0][j] = bA; g1s[1][j] = bB;
        __syncthreads();

        if (j < 2 * H_) {
            const int gi = j >> 7, r = j & (H_ - 1);
            const float f  = sigf(g1s[gi][r]);
            const float i_ = sigf(g1s[gi][H_ + r]);
            const float g  = tanhf(g1s[gi][2 * H_ + r]);
            const float o  = sigf(g1s[gi][3 * H_ + r]);
            const float c  = f * c1s[gi][r] + i_ * g;
            c1s[gi][r] = c;
            h1s[gi][r] = tanhf(c) * o;
        }
        __syncthreads();

        if (j < 2 * V_ * 8) {
            int q = j;
            const int gi = (q >= V_ * 8) ? 1 : 0;
            q -= gi * V_ * 8;
            const int v = q >> 3, kk = q & 7;
            float p = 0.f;
#pragma unroll
            for (int k = kk * 16; k < kk * 16 + 16; ++k)
                p += h1s[gi][k] * whyS[k * V_ + v];
            pb[gi][v][kk] = p;
        }
        __syncthreads();

        if (j < 2 * V_) {
            const int gi = (j >= V_) ? 1 : 0;
            const int v  = j - gi * V_;
            float s = byS[v];
#pragma unroll
            for (int q = 0; q < 8; ++q) s += pb[gi][v][q];
            (gi ? outB : outA)[t * V_ + v] = s;
        }
        __syncthreads();
    }
}

// ---------------- host ----------------
extern "C" void kernel_launch(void* const* d_in, const int* in_sizes, int n_in,
                              void* d_out, int out_size, void* d_ws, size_t ws_size,
                              hipStream_t stream)
{
    const int*   x   = (const int*)  d_in[0];
    const float* emb = (const float*)d_in[1];
    const float* wx0 = (const float*)d_in[2];
    const float* wh0 = (const float*)d_in[3];
    const float* b0  = (const float*)d_in[4];
    const float* wx1 = (const float*)d_in[5];
    const float* wh1 = (const float*)d_in[6];
    const float* b1  = (const float*)d_in[7];
    const float* why = (const float*)d_in[8];
    const float* by  = (const float*)d_in[9];
    float* out = (float*)d_out;
    float* wsf = (float*)d_ws;

    const size_t tabF   = (size_t)V_ * G4;       // 13824 floats
    const size_t stateF = (size_t)4 * B_ * H_;   // 131072 floats

    int TC = 0;
    for (int tc = T_; tc >= 32; tc >>= 1) {
        const size_t need = (tabF + stateF + (size_t)B_ * tc * (H_ + G4)) * 4;
        if (need <= ws_size) { TC = tc; break; }
    }

    float* table0 = wsf;
    build_table0<<<dim3(V_), dim3(G4), 0, stream>>>(emb, wx0, b0, table0);

    if (TC == 0) {
        // ws too small for phases: round-1 streaming fallback
        lstm_persist<<<dim3(B_ / 2), dim3(G4), 0, stream>>>(
            x, table0, wh0, wx1, wh1, b1, why, by, out);
        return;
    }

    float* h0st   = wsf + tabF;
    float* c0st   = h0st + (size_t)B_ * H_;
    float* h1st   = c0st + (size_t)B_ * H_;
    float* c1st   = h1st + (size_t)B_ * H_;
    float* h0buf  = c1st + (size_t)B_ * H_;
    float* xg1buf = h0buf + (size_t)B_ * TC * H_;

    hipMemsetAsync(h0st, 0, stateF * sizeof(float), stream);

    const int NC = T_ / TC;
    for (int c = 0; c < NC; ++c) {
        const int t0 = c * TC;
        lstm_l0_chunk<<<dim3(B_), dim3(G4), 0, stream>>>(
            x, table0, wh0, h0st, c0st, h0buf, t0, TC);
        gemm_xg1<<<dim3(4 * TC), dim3(G4), 0, stream>>>(
            h0buf, wx1, b1, xg1buf);
        lstm_l1_chunk<<<dim3(B_), dim3(G4), 0, stream>>>(
            xg1buf, wh1, why, by, h1st, c1st, out, t0, TC);
    }
}

// Round 5
// 3032.288 us; speedup vs baseline: 3.4915x; 1.8520x over previous
//
#include <hip/hip_runtime.h>

// MultiLayerLSTM: B=256, T=1024, V=27, E=64, H=128 (4H=512)
// Round 5: design for the 128-VGPR budget instead of fighting the allocator.
//   Evidence r2-r4: allocator pins recurrent kernels at 128 VGPRs regardless
//   of launch_bounds; 128 weights/thread + temps > 128 -> in-loop spill
//   (411 MB/dispatch scratch writes). Fix:
//   - Split-K: 1024 thr/block, thread (col, h) holds 64 named weight scalars
//     (k in [64h,64h+64)); halves combined via LDS psum[1024]. ~90 live regs.
//   - y-projection moved out of l1 into proj_y (separate kernel, h1 staged
//     in ws) -> l1 loop is pure gates like l0.
// Phases: P0 table, P1 l0 (wh0 regs), P2 GEMM xg1=h0@wx1+b1, P3 l1 (wh1 regs),
// P4 proj_y. Fallback to round-1 streaming kernel if ws too small.

#define B_  256
#define T_  1024
#define V_  27
#define E_  64
#define H_  128
#define G4  512   // 4*H

#define REPEAT16(M) M(0) M(1) M(2) M(3) M(4) M(5) M(6) M(7) \
                    M(8) M(9) M(10) M(11) M(12) M(13) M(14) M(15)

// 4 named weight scalars per K (row = 64*h + 4K+q, col fixed)
#define DECLW(K) float w##K##x, w##K##y, w##K##z, w##K##w;
#define LOADW(K) w##K##x = wbase[(size_t)((K)*4+0)*G4]; \
                 w##K##y = wbase[(size_t)((K)*4+1)*G4]; \
                 w##K##z = wbase[(size_t)((K)*4+2)*G4]; \
                 w##K##w = wbase[(size_t)((K)*4+3)*G4];
#define FMA4(K) { const float4 hv = hv4p[(K)]; \
                  a0 = fmaf(hv.x, w##K##x, a0); \
                  a1 = fmaf(hv.y, w##K##y, a1); \
                  a2 = fmaf(hv.z, w##K##z, a2); \
                  a3 = fmaf(hv.w, w##K##w, a3); }

__device__ __forceinline__ float sigf(float x) { return 1.0f / (1.0f + expf(-x)); }

// ---------------- P0: token table ----------------
__global__ __launch_bounds__(G4)
void build_table0(const float* __restrict__ emb,
                  const float* __restrict__ wx0,
                  const float* __restrict__ b0,
                  float* __restrict__ table0)
{
    const int v = blockIdx.x;        // 0..26
    const int j = threadIdx.x;       // 0..511
    __shared__ float e[E_];
    if (j < E_) e[j] = emb[v * E_ + j];
    __syncthreads();
    float s = b0[j];
#pragma unroll 8
    for (int k = 0; k < E_; ++k) s += e[k] * wx0[k * G4 + j];
    table0[v * G4 + j] = s;
}

// ---------------- P1: layer-0 recurrence, split-K ----------------
__global__ __launch_bounds__(1024, 1)
void lstm_l0_chunk(const int* __restrict__ x,
                   const float* __restrict__ table0,
                   const float* __restrict__ wh0,
                   float* __restrict__ h0st, float* __restrict__ c0st,
                   float* __restrict__ h0buf,
                   int t0, int TC)
{
    const int j   = threadIdx.x;      // 0..1023
    const int col = j & (G4 - 1);     // gate column
    const int h   = j >> 9;           // k-half 0/1
    const int b   = blockIdx.x;

    __shared__ __align__(16) float hS[H_];
    __shared__ float cS[H_];
    __shared__ float psum[1024];
    __shared__ float tabS[V_ * G4];   // 55296 B

    const float* wbase = wh0 + (size_t)(h * 64) * G4 + col;
    REPEAT16(DECLW)
    REPEAT16(LOADW)
    for (int e = j; e < V_ * G4; e += 1024) tabS[e] = table0[e];
    if (j < H_) { hS[j] = h0st[b * H_ + j]; cS[j] = c0st[b * H_ + j]; }
    __syncthreads();

    const int* xb = x + (size_t)b * T_ + t0;
    float* hob = h0buf + (size_t)b * TC * H_;
    const float4* hv4p = reinterpret_cast<const float4*>(hS) + h * 16;

    int idx_next = xb[0];
    for (int t = 0; t < TC; ++t) {
        const int idx = idx_next;
        if (t + 1 < TC) idx_next = xb[t + 1];

        float a0 = 0.f, a1 = 0.f, a2 = 0.f, a3 = 0.f;
        REPEAT16(FMA4)
        float s = (a0 + a1) + (a2 + a3);
        if (h == 0) s += tabS[idx * G4 + col];
        psum[j] = s;
        __syncthreads();

        if (j < H_) {
            const float f  = sigf(psum[j]       + psum[512 + j]);
            const float i_ = sigf(psum[128 + j] + psum[640 + j]);
            const float g  = tanhf(psum[256 + j] + psum[768 + j]);
            const float o  = sigf(psum[384 + j] + psum[896 + j]);
            const float c  = f * cS[j] + i_ * g;
            cS[j] = c;
            const float hh = tanhf(c) * o;
            hS[j] = hh;
            hob[(size_t)t * H_ + j] = hh;
        }
        __syncthreads();
    }
    if (j < H_) { h0st[b * H_ + j] = hS[j]; c0st[b * H_ + j] = cS[j]; }
}

// ---------------- P2: xg1 = h0 @ wx1 + b1 ----------------
// block: 64 rows x 512 cols; thread: 16 rows x 4 cols (acc[4][16])
__global__ __launch_bounds__(G4, 2)
void gemm_xg1(const float* __restrict__ h0buf,
              const float* __restrict__ wx1,
              const float* __restrict__ b1,
              float* __restrict__ xg1)
{
    const int j  = threadIdx.x;
    const size_t m0 = (size_t)blockIdx.x * 64;
    const int c  = j & 127;          // cols c, c+128, c+256, c+384
    const int rg = j >> 7;           // rows rg*16 .. rg*16+15

    __shared__ __align__(16) float aT[64 * 132];   // row-major [r][k], pad 132

#pragma unroll
    for (int i = 0; i < 4; ++i) {
        const int e  = i * G4 + j;       // float4 index 0..2047
        const int r  = e >> 5;           // 32 float4 per row
        const int k4 = e & 31;
        const float4 v = *reinterpret_cast<const float4*>(&h0buf[(m0 + r) * H_ + k4 * 4]);
        *reinterpret_cast<float4*>(&aT[r * 132 + k4 * 4]) = v;
    }
    __syncthreads();

    float acc[4][16];
#pragma unroll
    for (int cc = 0; cc < 4; ++cc)
#pragma unroll
        for (int rr = 0; rr < 16; ++rr) acc[cc][rr] = 0.f;

    for (int k4 = 0; k4 < 32; ++k4) {
        float bv[4][4];   // [kk][cc]
#pragma unroll
        for (int kk = 0; kk < 4; ++kk)
#pragma unroll
            for (int cc = 0; cc < 4; ++cc)
                bv[kk][cc] = wx1[(size_t)(k4 * 4 + kk) * G4 + cc * 128 + c];
#pragma unroll
        for (int rr = 0; rr < 16; ++rr) {
            const float4 av = *reinterpret_cast<const float4*>(&aT[(rg * 16 + rr) * 132 + k4 * 4]);
#pragma unroll
            for (int cc = 0; cc < 4; ++cc) {
                acc[cc][rr] = fmaf(av.x, bv[0][cc], acc[cc][rr]);
                acc[cc][rr] = fmaf(av.y, bv[1][cc], acc[cc][rr]);
                acc[cc][rr] = fmaf(av.z, bv[2][cc], acc[cc][rr]);
                acc[cc][rr] = fmaf(av.w, bv[3][cc], acc[cc][rr]);
            }
        }
    }

    float b1v[4];
#pragma unroll
    for (int cc = 0; cc < 4; ++cc) b1v[cc] = b1[cc * 128 + c];
#pragma unroll
    for (int rr = 0; rr < 16; ++rr) {
        const size_t row = m0 + rg * 16 + rr;
#pragma unroll
        for (int cc = 0; cc < 4; ++cc)
            xg1[row * G4 + cc * 128 + c] = acc[cc][rr] + b1v[cc];
    }
}

// ---------------- P3: layer-1 recurrence, split-K ----------------
__global__ __launch_bounds__(1024, 1)
void lstm_l1_chunk(const float* __restrict__ xg1,
                   const float* __restrict__ wh1,
                   float* __restrict__ h1st, float* __restrict__ c1st,
                   float* __restrict__ h1buf,
                   int TC)
{
    const int j   = threadIdx.x;
    const int col = j & (G4 - 1);
    const int h   = j >> 9;
    const int b   = blockIdx.x;

    __shared__ __align__(16) float hS[H_];
    __shared__ float cS[H_];
    __shared__ float psum[1024];

    const float* wbase = wh1 + (size_t)(h * 64) * G4 + col;
    REPEAT16(DECLW)
    REPEAT16(LOADW)
    if (j < H_) { hS[j] = h1st[b * H_ + j]; cS[j] = c1st[b * H_ + j]; }
    __syncthreads();

    const float* xgb = xg1 + (size_t)b * TC * G4;
    float* hob = h1buf + (size_t)b * TC * H_;
    const float4* hv4p = reinterpret_cast<const float4*>(hS) + h * 16;

    float xv_next = (h == 0) ? xgb[col] : 0.f;
    for (int t = 0; t < TC; ++t) {
        const float xv = xv_next;
        if (h == 0 && t + 1 < TC) xv_next = xgb[(size_t)(t + 1) * G4 + col];

        float a0 = 0.f, a1 = 0.f, a2 = 0.f, a3 = 0.f;
        REPEAT16(FMA4)
        float s = (a0 + a1) + (a2 + a3);
        if (h == 0) s += xv;              // xg1 already includes b1
        psum[j] = s;
        __syncthreads();

        if (j < H_) {
            const float f  = sigf(psum[j]       + psum[512 + j]);
            const float i_ = sigf(psum[128 + j] + psum[640 + j]);
            const float g  = tanhf(psum[256 + j] + psum[768 + j]);
            const float o  = sigf(psum[384 + j] + psum[896 + j]);
            const float c  = f * cS[j] + i_ * g;
            cS[j] = c;
            const float hh = tanhf(c) * o;
            hS[j] = hh;
            hob[(size_t)t * H_ + j] = hh;
        }
        __syncthreads();
    }
    if (j < H_) { h1st[b * H_ + j] = hS[j]; c1st[b * H_ + j] = cS[j]; }
}

// ---------------- P4: y = h1 @ why + by ----------------
// grid = B blocks; block = 256 threads; thread -> one (b,t) row per pass.
__global__ __launch_bounds__(256)
void proj_y(const float* __restrict__ h1buf,
            const float* __restrict__ why,
            const float* __restrict__ by,
            float* __restrict__ out,
            int t0, int TC)
{
    const int tid = threadIdx.x;
    const int b   = blockIdx.x;

    __shared__ __align__(16) float whyS[V_][H_];   // [v][k], broadcast-read
    __shared__ float byS[V_];
    __shared__ float yS[256][29];                  // pad 29: conflict-free stage

    for (int e = tid; e < V_ * H_; e += 256) {
        const int v = e / H_, k = e - v * H_;
        whyS[v][k] = why[k * V_ + v];
    }
    if (tid < V_) byS[tid] = by[tid];
    __syncthreads();

    const float* hb  = h1buf + (size_t)b * TC * H_;
    float* outb      = out + ((size_t)b * T_ + t0) * V_;

    for (int tt0 = 0; tt0 < TC; tt0 += 256) {
        const int tt = tt0 + tid;
        if (tt < TC) {
            float acc[V_];
#pragma unroll
            for (int v = 0; v < V_; ++v) acc[v] = byS[v];
            const float4* hr = reinterpret_cast<const float4*>(hb + (size_t)tt * H_);
#pragma unroll 4
            for (int k4 = 0; k4 < 32; ++k4) {
                const float4 hv = hr[k4];
#pragma unroll
                for (int v = 0; v < V_; ++v) {
                    const float4 wv = *reinterpret_cast<const float4*>(&whyS[v][k4 * 4]);
                    acc[v] = fmaf(hv.x, wv.x,
                             fmaf(hv.y, wv.y,
                             fmaf(hv.z, wv.z,
                             fmaf(hv.w, wv.w, acc[v]))));
                }
            }
#pragma unroll
            for (int v = 0; v < V_; ++v) yS[tid][v] = acc[v];
        }
        __syncthreads();
        const int nrow = (TC - tt0 < 256) ? (TC - tt0) : 256;
        const int n = nrow * V_;
        float* od = outb + (size_t)tt0 * V_;
        for (int i = tid; i < n; i += 256) {
            const int r = i / V_, v = i - r * V_;
            od[i] = yS[r][v];
        }
        __syncthreads();
    }
}

// ---------------- fallback: round-1 streaming kernel ----------------
__global__ __launch_bounds__(G4, 1)
void lstm_persist(const int* __restrict__ x,
                  const float* __restrict__ table0,
                  const float* __restrict__ wh0,
                  const float* __restrict__ wx1,
                  const float* __restrict__ wh1,
                  const float* __restrict__ b1,
                  const float* __restrict__ why,
                  const float* __restrict__ by,
                  float* __restrict__ out)
{
    const int j  = threadIdx.x;
    const int bb = blockIdx.x * 2;

    __shared__ float h0s[2][H_], c0s[2][H_], h1s[2][H_], c1s[2][H_];
    __shared__ float hcat[2][2 * H_];
    __shared__ float g0s[2][G4], g1s[2][G4];
    __shared__ float whyS[H_ * V_];
    __shared__ float b1S[G4];
    __shared__ float byS[V_];
    __shared__ float pb[2][V_][8];

    for (int i = j; i < H_ * V_; i += G4) whyS[i] = why[i];
    b1S[j] = b1[j];
    if (j < V_) byS[j] = by[j];
    if (j < H_) {
        h0s[0][j] = 0.f; h0s[1][j] = 0.f; c0s[0][j] = 0.f; c0s[1][j] = 0.f;
        h1s[0][j] = 0.f; h1s[1][j] = 0.f; c1s[0][j] = 0.f; c1s[1][j] = 0.f;
    }
    __syncthreads();

    const int* xA = x + (size_t)(bb + 0) * T_;
    const int* xB = x + (size_t)(bb + 1) * T_;
    float* outA = out + (size_t)(bb + 0) * T_ * V_;
    float* outB = out + (size_t)(bb + 1) * T_ * V_;

    for (int t = 0; t < T_; ++t) {
        const int ia = xA[t];
        const int ib = xB[t];
        float aA = table0[ia * G4 + j];
        float aB = table0[ib * G4 + j];
#pragma unroll 8
        for (int k = 0; k < H_; ++k) {
            const float w = wh0[k * G4 + j];
            aA += h0s[0][k] * w;
            aB += h0s[1][k] * w;
        }
        g0s[0][j] = aA; g0s[1][j] = aB;
        __syncthreads();

        if (j < 2 * H_) {
            const int gi = j >> 7, r = j & (H_ - 1);
            const float f  = sigf(g0s[gi][r]);
            const float i_ = sigf(g0s[gi][H_ + r]);
            const float g  = tanhf(g0s[gi][2 * H_ + r]);
            const float o  = sigf(g0s[gi][3 * H_ + r]);
            const float c  = f * c0s[gi][r] + i_ * g;
            c0s[gi][r] = c;
            const float h = tanhf(c) * o;
            h0s[gi][r] = h;
            hcat[gi][r] = h;
            hcat[gi][H_ + r] = h1s[gi][r];
        }
        __syncthreads();

        float bA = b1S[j];
        float bB = bA;
#pragma unroll 8
        for (int k = 0; k < H_; ++k) {
            const float w = wx1[k * G4 + j];
            bA += hcat[0][k] * w;
            bB += hcat[1][k] * w;
        }
#pragma unroll 8
        for (int k = 0; k < H_; ++k) {
            const float w = wh1[k * G4 + j];
            bA += hcat[0][H_ + k] * w;
            bB += hcat[1][H_ + k] * w;
        }
        g1s[0][j] = bA; g1s[1][j] = bB;
        __syncthreads();

        if (j < 2 * H_) {
            const int gi = j >> 7, r = j & (H_ - 1);
            const float f  = sigf(g1s[gi][r]);
            const float i_ = sigf(g1s[gi][H_ + r]);
            const float g  = tanhf(g1s[gi][2 * H_ + r]);
            const float o  = sigf(g1s[gi][3 * H_ + r]);
            const float c  = f * c1s[gi][r] + i_ * g;
            c1s[gi][r] = c;
            h1s[gi][r] = tanhf(c) * o;
        }
        __syncthreads();

        if (j < 2 * V_ * 8) {
            int q = j;
            const int gi = (q >= V_ * 8) ? 1 : 0;
            q -= gi * V_ * 8;
            const int v = q >> 3, kk = q & 7;
            float p = 0.f;
#pragma unroll
            for (int k = kk * 16; k < kk * 16 + 16; ++k)
                p += h1s[gi][k] * whyS[k * V_ + v];
            pb[gi][v][kk] = p;
        }
        __syncthreads();

        if (j < 2 * V_) {
            const int gi = (j >= V_) ? 1 : 0;
            const int v  = j - gi * V_;
            float s = byS[v];
#pragma unroll
            for (int q = 0; q < 8; ++q) s += pb[gi][v][q];
            (gi ? outB : outA)[t * V_ + v] = s;
        }
        __syncthreads();
    }
}

// ---------------- host ----------------
extern "C" void kernel_launch(void* const* d_in, const int* in_sizes, int n_in,
                              void* d_out, int out_size, void* d_ws, size_t ws_size,
                              hipStream_t stream)
{
    const int*   x   = (const int*)  d_in[0];
    const float* emb = (const float*)d_in[1];
    const float* wx0 = (const float*)d_in[2];
    const float* wh0 = (const float*)d_in[3];
    const float* b0  = (const float*)d_in[4];
    const float* wx1 = (const float*)d_in[5];
    const float* wh1 = (const float*)d_in[6];
    const float* b1  = (const float*)d_in[7];
    const float* why = (const float*)d_in[8];
    const float* by  = (const float*)d_in[9];
    float* out = (float*)d_out;
    float* wsf = (float*)d_ws;

    const size_t tabF   = (size_t)V_ * G4;       // 13824 floats
    const size_t stateF = (size_t)4 * B_ * H_;   // 131072 floats

    int TC = 0;
    for (int tc = T_; tc >= 32; tc >>= 1) {
        // per-chunk buffers: h0buf (H) + xg1buf (G4) + h1buf (H) per (b,t)
        const size_t need = (tabF + stateF + (size_t)B_ * tc * (H_ + G4 + H_)) * 4;
        if (need <= ws_size) { TC = tc; break; }
    }

    float* table0 = wsf;
    build_table0<<<dim3(V_), dim3(G4), 0, stream>>>(emb, wx0, b0, table0);

    if (TC == 0) {
        lstm_persist<<<dim3(B_ / 2), dim3(G4), 0, stream>>>(
            x, table0, wh0, wx1, wh1, b1, why, by, out);
        return;
    }

    float* h0st   = wsf + tabF;
    float* c0st   = h0st + (size_t)B_ * H_;
    float* h1st   = c0st + (size_t)B_ * H_;
    float* c1st   = h1st + (size_t)B_ * H_;
    float* h0buf  = c1st + (size_t)B_ * H_;
    float* xg1buf = h0buf + (size_t)B_ * TC * H_;
    float* h1buf  = xg1buf + (size_t)B_ * TC * G4;

    hipMemsetAsync(h0st, 0, stateF * sizeof(float), stream);

    const int NC = T_ / TC;
    for (int c = 0; c < NC; ++c) {
        const int t0 = c * TC;
        lstm_l0_chunk<<<dim3(B_), dim3(1024), 0, stream>>>(
            x, table0, wh0, h0st, c0st, h0buf, t0, TC);
        gemm_xg1<<<dim3(4 * TC), dim3(G4), 0, stream>>>(
            h0buf, wx1, b1, xg1buf);
        lstm_l1_chunk<<<dim3(B_), dim3(1024), 0, stream>>>(
            xg1buf, wh1, h1st, c1st, h1buf, TC);
        proj_y<<<dim3(B_), dim3(256), 0, stream>>>(
            h1buf, why, by, out, t0, TC);
    }
}

// Round 6
// 2942.635 us; speedup vs baseline: 3.5979x; 1.0305x over previous
//
#include <hip/hip_runtime.h>

// MultiLayerLSTM: B=256, T=1024, V=27, E=64, H=128 (4H=512)
// Round 6: recurrence micro-architecture rework.
//  - r5 showed VGPR_Count=60 for 64 named weights -> compiler AGPR-offloaded
//    them ((1024,1) let the heuristic target 64 regs); every step paid ~64
//    v_accvgpr_read/thread. Fix: __launch_bounds__(1024,4) -> 128-reg cap.
//  - DS pipe was ~3072 cyc/step (256 broadcast ds_read_b128 @ ~12cyc). Fix:
//    thread = (col-pair, k-quarter): 8 reads/thread (128/CU/step), quad
//    reduction via DPP quad_perm (VALU, replaces psum LDS phase entirely).
//  - gate activations computed in the wide phase (q==0 lanes); narrow phase
//    is only c,h + tanhf.
// Phases: P0 table, P1 l0 (wh0 regs), P2 GEMM xg1=h0@wx1+b1, P3 l1 (wh1 regs),
// P4 proj_y. Fallback to round-1 streaming kernel if ws too small.

#define B_  256
#define T_  1024
#define V_  27
#define E_  64
#define H_  128
#define G4  512   // 4*H

#define REPEAT8(M) M(0) M(1) M(2) M(3) M(4) M(5) M(6) M(7)

// per group G (k-offsets 4G..4G+3 inside this thread's k-quarter):
// a = weights for col 2p, b = weights for col 2p+1
#define DECLWQ(G) float a##G##0, a##G##1, a##G##2, a##G##3, \
                        b##G##0, b##G##1, b##G##2, b##G##3;
#define LOADWQ(G) { \
    const float2 t0 = *reinterpret_cast<const float2*>(&wrow[(size_t)((G)*4+0)*G4]); \
    const float2 t1 = *reinterpret_cast<const float2*>(&wrow[(size_t)((G)*4+1)*G4]); \
    const float2 t2 = *reinterpret_cast<const float2*>(&wrow[(size_t)((G)*4+2)*G4]); \
    const float2 t3 = *reinterpret_cast<const float2*>(&wrow[(size_t)((G)*4+3)*G4]); \
    a##G##0 = t0.x; b##G##0 = t0.y; a##G##1 = t1.x; b##G##1 = t1.y; \
    a##G##2 = t2.x; b##G##2 = t2.y; a##G##3 = t3.x; b##G##3 = t3.y; }
#define FMAQ(G) { const float4 hv = hq4[(G)]; \
    sA0 = fmaf(hv.x, a##G##0, sA0); sB0 = fmaf(hv.x, b##G##0, sB0); \
    sA1 = fmaf(hv.y, a##G##1, sA1); sB1 = fmaf(hv.y, b##G##1, sB1); \
    sA0 = fmaf(hv.z, a##G##2, sA0); sB0 = fmaf(hv.z, b##G##2, sB0); \
    sA1 = fmaf(hv.w, a##G##3, sA1); sB1 = fmaf(hv.w, b##G##3, sB1); }

__device__ __forceinline__ float sigf(float x) { return 1.0f / (1.0f + expf(-x)); }

// butterfly sum over the 4 lanes of a quad (DPP quad_perm, pure VALU)
__device__ __forceinline__ float quad_sum(float v) {
    v += __int_as_float(__builtin_amdgcn_update_dpp(
            0, __float_as_int(v), 0xB1, 0xF, 0xF, true));   // xor 1
    v += __int_as_float(__builtin_amdgcn_update_dpp(
            0, __float_as_int(v), 0x4E, 0xF, 0xF, true));   // xor 2
    return v;
}

// ---------------- P0: token table ----------------
__global__ __launch_bounds__(G4)
void build_table0(const float* __restrict__ emb,
                  const float* __restrict__ wx0,
                  const float* __restrict__ b0,
                  float* __restrict__ table0)
{
    const int v = blockIdx.x;        // 0..26
    const int j = threadIdx.x;       // 0..511
    __shared__ float e[E_];
    if (j < E_) e[j] = emb[v * E_ + j];
    __syncthreads();
    float s = b0[j];
#pragma unroll 8
    for (int k = 0; k < E_; ++k) s += e[k] * wx0[k * G4 + j];
    table0[v * G4 + j] = s;
}

// ---------------- P1: layer-0 recurrence (col-pair x k-quarter) ----------------
__global__ __launch_bounds__(1024, 4)
void lstm_l0_chunk(const int* __restrict__ x,
                   const float* __restrict__ table0,
                   const float* __restrict__ wh0,
                   float* __restrict__ h0st, float* __restrict__ c0st,
                   float* __restrict__ h0buf,
                   int t0, int TC)
{
    const int j  = threadIdx.x;       // 0..1023
    const int p  = j >> 2;            // col-pair 0..255
    const int q  = j & 3;             // k-quarter
    const int b  = blockIdx.x;
    const int c0 = 2 * p;

    __shared__ __align__(16) float hS[H_];
    __shared__ float cS[H_];
    __shared__ __align__(8) float act[G4];
    __shared__ float tabS[V_ * G4];   // 55296 B

    const float* wrow = wh0 + (size_t)(32 * q) * G4 + c0;
    REPEAT8(DECLWQ)
    REPEAT8(LOADWQ)
    for (int e = j; e < V_ * G4; e += 1024) tabS[e] = table0[e];
    if (j < H_) { hS[j] = h0st[b * H_ + j]; cS[j] = c0st[b * H_ + j]; }
    __syncthreads();

    const int* xb = x + (size_t)b * T_ + t0;
    float* hob = h0buf + (size_t)b * TC * H_;
    const float4* hq4 = reinterpret_cast<const float4*>(hS) + q * 8;
    const bool isg = (p >> 6) == 2;   // cols 256..383 = g-gate (tanh)

    int idx_next = xb[0];
    for (int t = 0; t < TC; ++t) {
        const int idx = idx_next;
        if (t + 1 < TC) idx_next = xb[t + 1];

        float sA0 = 0.f, sA1 = 0.f, sB0 = 0.f, sB1 = 0.f;
        REPEAT8(FMAQ)
        float sA = quad_sum(sA0 + sA1);
        float sB = quad_sum(sB0 + sB1);
        if (q == 0) {
            const float2 tv = *reinterpret_cast<const float2*>(&tabS[idx * G4 + c0]);
            sA += tv.x; sB += tv.y;
            const float aA = isg ? tanhf(sA) : sigf(sA);
            const float aB = isg ? tanhf(sB) : sigf(sB);
            *reinterpret_cast<float2*>(&act[c0]) = make_float2(aA, aB);
        }
        __syncthreads();

        if (j < H_) {
            const float f  = act[j];
            const float i_ = act[H_ + j];
            const float g  = act[2 * H_ + j];
            const float o  = act[3 * H_ + j];
            const float c  = f * cS[j] + i_ * g;
            cS[j] = c;
            const float hh = tanhf(c) * o;
            hS[j] = hh;
            hob[(size_t)t * H_ + j] = hh;
        }
        __syncthreads();
    }
    if (j < H_) { h0st[b * H_ + j] = hS[j]; c0st[b * H_ + j] = cS[j]; }
}

// ---------------- P2: xg1 = h0 @ wx1 + b1 ----------------
// block: 64 rows x 512 cols; thread: 16 rows x 4 cols (acc[4][16])
__global__ __launch_bounds__(G4, 2)
void gemm_xg1(const float* __restrict__ h0buf,
              const float* __restrict__ wx1,
              const float* __restrict__ b1,
              float* __restrict__ xg1)
{
    const int j  = threadIdx.x;
    const size_t m0 = (size_t)blockIdx.x * 64;
    const int c  = j & 127;          // cols c, c+128, c+256, c+384
    const int rg = j >> 7;           // rows rg*16 .. rg*16+15

    __shared__ __align__(16) float aT[64 * 132];   // row-major [r][k], pad 132

#pragma unroll
    for (int i = 0; i < 4; ++i) {
        const int e  = i * G4 + j;       // float4 index 0..2047
        const int r  = e >> 5;           // 32 float4 per row
        const int k4 = e & 31;
        const float4 v = *reinterpret_cast<const float4*>(&h0buf[(m0 + r) * H_ + k4 * 4]);
        *reinterpret_cast<float4*>(&aT[r * 132 + k4 * 4]) = v;
    }
    __syncthreads();

    float acc[4][16];
#pragma unroll
    for (int cc = 0; cc < 4; ++cc)
#pragma unroll
        for (int rr = 0; rr < 16; ++rr) acc[cc][rr] = 0.f;

    for (int k4 = 0; k4 < 32; ++k4) {
        float bv[4][4];   // [kk][cc]
#pragma unroll
        for (int kk = 0; kk < 4; ++kk)
#pragma unroll
            for (int cc = 0; cc < 4; ++cc)
                bv[kk][cc] = wx1[(size_t)(k4 * 4 + kk) * G4 + cc * 128 + c];
#pragma unroll
        for (int rr = 0; rr < 16; ++rr) {
            const float4 av = *reinterpret_cast<const float4*>(&aT[(rg * 16 + rr) * 132 + k4 * 4]);
#pragma unroll
            for (int cc = 0; cc < 4; ++cc) {
                acc[cc][rr] = fmaf(av.x, bv[0][cc], acc[cc][rr]);
                acc[cc][rr] = fmaf(av.y, bv[1][cc], acc[cc][rr]);
                acc[cc][rr] = fmaf(av.z, bv[2][cc], acc[cc][rr]);
                acc[cc][rr] = fmaf(av.w, bv[3][cc], acc[cc][rr]);
            }
        }
    }

    float b1v[4];
#pragma unroll
    for (int cc = 0; cc < 4; ++cc) b1v[cc] = b1[cc * 128 + c];
#pragma unroll
    for (int rr = 0; rr < 16; ++rr) {
        const size_t row = m0 + rg * 16 + rr;
#pragma unroll
        for (int cc = 0; cc < 4; ++cc)
            xg1[row * G4 + cc * 128 + c] = acc[cc][rr] + b1v[cc];
    }
}

// ---------------- P3: layer-1 recurrence (col-pair x k-quarter) ----------------
__global__ __launch_bounds__(1024, 4)
void lstm_l1_chunk(const float* __restrict__ xg1,
                   const float* __restrict__ wh1,
                   float* __restrict__ h1st, float* __restrict__ c1st,
                   float* __restrict__ h1buf,
                   int TC)
{
    const int j  = threadIdx.x;
    const int p  = j >> 2;
    const int q  = j & 3;
    const int b  = blockIdx.x;
    const int c0 = 2 * p;

    __shared__ __align__(16) float hS[H_];
    __shared__ float cS[H_];
    __shared__ __align__(8) float act[G4];

    const float* wrow = wh1 + (size_t)(32 * q) * G4 + c0;
    REPEAT8(DECLWQ)
    REPEAT8(LOADWQ)
    if (j < H_) { hS[j] = h1st[b * H_ + j]; cS[j] = c1st[b * H_ + j]; }
    __syncthreads();

    const float* xgb = xg1 + (size_t)b * TC * G4;
    float* hob = h1buf + (size_t)b * TC * H_;
    const float4* hq4 = reinterpret_cast<const float4*>(hS) + q * 8;
    const bool isg = (p >> 6) == 2;

    float2 xv_next = make_float2(0.f, 0.f);
    if (q == 0) xv_next = *reinterpret_cast<const float2*>(&xgb[c0]);
    for (int t = 0; t < TC; ++t) {
        const float2 xv = xv_next;
        if (q == 0 && t + 1 < TC)
            xv_next = *reinterpret_cast<const float2*>(&xgb[(size_t)(t + 1) * G4 + c0]);

        float sA0 = 0.f, sA1 = 0.f, sB0 = 0.f, sB1 = 0.f;
        REPEAT8(FMAQ)
        float sA = quad_sum(sA0 + sA1);
        float sB = quad_sum(sB0 + sB1);
        if (q == 0) {
            sA += xv.x; sB += xv.y;      // xg1 already includes b1
            const float aA = isg ? tanhf(sA) : sigf(sA);
            const float aB = isg ? tanhf(sB) : sigf(sB);
            *reinterpret_cast<float2*>(&act[c0]) = make_float2(aA, aB);
        }
        __syncthreads();

        if (j < H_) {
            const float f  = act[j];
            const float i_ = act[H_ + j];
            const float g  = act[2 * H_ + j];
            const float o  = act[3 * H_ + j];
            const float c  = f * cS[j] + i_ * g;
            cS[j] = c;
            const float hh = tanhf(c) * o;
            hS[j] = hh;
            hob[(size_t)t * H_ + j] = hh;
        }
        __syncthreads();
    }
    if (j < H_) { h1st[b * H_ + j] = hS[j]; c1st[b * H_ + j] = cS[j]; }
}

// ---------------- P4: y = h1 @ why + by ----------------
__global__ __launch_bounds__(256)
void proj_y(const float* __restrict__ h1buf,
            const float* __restrict__ why,
            const float* __restrict__ by,
            float* __restrict__ out,
            int t0, int TC)
{
    const int tid = threadIdx.x;
    const int b   = blockIdx.x;

    __shared__ __align__(16) float whyS[V_][H_];   // [v][k], broadcast-read
    __shared__ float byS[V_];
    __shared__ float yS[256][29];                  // pad 29: conflict-free stage

    for (int e = tid; e < V_ * H_; e += 256) {
        const int v = e / H_, k = e - v * H_;
        whyS[v][k] = why[k * V_ + v];
    }
    if (tid < V_) byS[tid] = by[tid];
    __syncthreads();

    const float* hb  = h1buf + (size_t)b * TC * H_;
    float* outb      = out + ((size_t)b * T_ + t0) * V_;

    for (int tt0 = 0; tt0 < TC; tt0 += 256) {
        const int tt = tt0 + tid;
        if (tt < TC) {
            float acc[V_];
#pragma unroll
            for (int v = 0; v < V_; ++v) acc[v] = byS[v];
            const float4* hr = reinterpret_cast<const float4*>(hb + (size_t)tt * H_);
#pragma unroll 4
            for (int k4 = 0; k4 < 32; ++k4) {
                const float4 hv = hr[k4];
#pragma unroll
                for (int v = 0; v < V_; ++v) {
                    const float4 wv = *reinterpret_cast<const float4*>(&whyS[v][k4 * 4]);
                    acc[v] = fmaf(hv.x, wv.x,
                             fmaf(hv.y, wv.y,
                             fmaf(hv.z, wv.z,
                             fmaf(hv.w, wv.w, acc[v]))));
                }
            }
#pragma unroll
            for (int v = 0; v < V_; ++v) yS[tid][v] = acc[v];
        }
        __syncthreads();
        const int nrow = (TC - tt0 < 256) ? (TC - tt0) : 256;
        const int n = nrow * V_;
        float* od = outb + (size_t)tt0 * V_;
        for (int i = tid; i < n; i += 256) {
            const int r = i / V_, v = i - r * V_;
            od[i] = yS[r][v];
        }
        __syncthreads();
    }
}

// ---------------- fallback: round-1 streaming kernel ----------------
__global__ __launch_bounds__(G4, 1)
void lstm_persist(const int* __restrict__ x,
                  const float* __restrict__ table0,
                  const float* __restrict__ wh0,
                  const float* __restrict__ wx1,
                  const float* __restrict__ wh1,
                  const float* __restrict__ b1,
                  const float* __restrict__ why,
                  const float* __restrict__ by,
                  float* __restrict__ out)
{
    const int j  = threadIdx.x;
    const int bb = blockIdx.x * 2;

    __shared__ float h0s[2][H_], c0s[2][H_], h1s[2][H_], c1s[2][H_];
    __shared__ float hcat[2][2 * H_];
    __shared__ float g0s[2][G4], g1s[2][G4];
    __shared__ float whyS[H_ * V_];
    __shared__ float b1S[G4];
    __shared__ float byS[V_];
    __shared__ float pb[2][V_][8];

    for (int i = j; i < H_ * V_; i += G4) whyS[i] = why[i];
    b1S[j] = b1[j];
    if (j < V_) byS[j] = by[j];
    if (j < H_) {
        h0s[0][j] = 0.f; h0s[1][j] = 0.f; c0s[0][j] = 0.f; c0s[1][j] = 0.f;
        h1s[0][j] = 0.f; h1s[1][j] = 0.f; c1s[0][j] = 0.f; c1s[1][j] = 0.f;
    }
    __syncthreads();

    const int* xA = x + (size_t)(bb + 0) * T_;
    const int* xB = x + (size_t)(bb + 1) * T_;
    float* outA = out + (size_t)(bb + 0) * T_ * V_;
    float* outB = out + (size_t)(bb + 1) * T_ * V_;

    for (int t = 0; t < T_; ++t) {
        const int ia = xA[t];
        const int ib = xB[t];
        float aA = table0[ia * G4 + j];
        float aB = table0[ib * G4 + j];
#pragma unroll 8
        for (int k = 0; k < H_; ++k) {
            const float w = wh0[k * G4 + j];
            aA += h0s[0][k] * w;
            aB += h0s[1][k] * w;
        }
        g0s[0][j] = aA; g0s[1][j] = aB;
        __syncthreads();

        if (j < 2 * H_) {
            const int gi = j >> 7, r = j & (H_ - 1);
            const float f  = sigf(g0s[gi][r]);
            const float i_ = sigf(g0s[gi][H_ + r]);
            const float g  = tanhf(g0s[gi][2 * H_ + r]);
            const float o  = sigf(g0s[gi][3 * H_ + r]);
            const float c  = f * c0s[gi][r] + i_ * g;
            c0s[gi][r] = c;
            const float h = tanhf(c) * o;
            h0s[gi][r] = h;
            hcat[gi][r] = h;
            hcat[gi][H_ + r] = h1s[gi][r];
        }
        __syncthreads();

        float bA = b1S[j];
        float bB = bA;
#pragma unroll 8
        for (int k = 0; k < H_; ++k) {
            const float w = wx1[k * G4 + j];
            bA += hcat[0][k] * w;
            bB += hcat[1][k] * w;
        }
#pragma unroll 8
        for (int k = 0; k < H_; ++k) {
            const float w = wh1[k * G4 + j];
            bA += hcat[0][H_ + k] * w;
            bB += hcat[1][H_ + k] * w;
        }
        g1s[0][j] = bA; g1s[1][j] = bB;
        __syncthreads();

        if (j < 2 * H_) {
            const int gi = j >> 7, r = j & (H_ - 1);
            const float f  = sigf(g1s[gi][r]);
            const float i_ = sigf(g1s[gi][H_ + r]);
            const float g  = tanhf(g1s[gi][2 * H_ + r]);
            const float o  = sigf(g1s[gi][3 * H_ + r]);
            const float c  = f * c1s[gi][r] + i_ * g;
            c1s[gi][r] = c;
            h1s[gi][r] = tanhf(c) * o;
        }
        __syncthreads();

        if (j < 2 * V_ * 8) {
            int q = j;
            const int gi = (q >= V_ * 8) ? 1 : 0;
            q -= gi * V_ * 8;
            const int v = q >> 3, kk = q & 7;
            float p = 0.f;
#pragma unroll
            for (int k = kk * 16; k < kk * 16 + 16; ++k)
                p += h1s[gi][k] * whyS[k * V_ + v];
            pb[gi][v][kk] = p;
        }
        __syncthreads();

        if (j < 2 * V_) {
            const int gi = (j >= V_) ? 1 : 0;
            const int v  = j - gi * V_;
            float s = byS[v];
#pragma unroll
            for (int q = 0; q < 8; ++q) s += pb[gi][v][q];
            (gi ? outB : outA)[t * V_ + v] = s;
        }
        __syncthreads();
    }
}

// ---------------- host ----------------
extern "C" void kernel_launch(void* const* d_in, const int* in_sizes, int n_in,
                              void* d_out, int out_size, void* d_ws, size_t ws_size,
                              hipStream_t stream)
{
    const int*   x   = (const int*)  d_in[0];
    const float* emb = (const float*)d_in[1];
    const float* wx0 = (const float*)d_in[2];
    const float* wh0 = (const float*)d_in[3];
    const float* b0  = (const float*)d_in[4];
    const float* wx1 = (const float*)d_in[5];
    const float* wh1 = (const float*)d_in[6];
    const float* b1  = (const float*)d_in[7];
    const float* why = (const float*)d_in[8];
    const float* by  = (const float*)d_in[9];
    float* out = (float*)d_out;
    float* wsf = (float*)d_ws;

    const size_t tabF   = (size_t)V_ * G4;       // 13824 floats
    const size_t stateF = (size_t)4 * B_ * H_;   // 131072 floats

    int TC = 0;
    for (int tc = T_; tc >= 32; tc >>= 1) {
        // per-chunk buffers: h0buf (H) + xg1buf (G4) + h1buf (H) per (b,t)
        const size_t need = (tabF + stateF + (size_t)B_ * tc * (H_ + G4 + H_)) * 4;
        if (need <= ws_size) { TC = tc; break; }
    }

    float* table0 = wsf;
    build_table0<<<dim3(V_), dim3(G4), 0, stream>>>(emb, wx0, b0, table0);

    if (TC == 0) {
        lstm_persist<<<dim3(B_ / 2), dim3(G4), 0, stream>>>(
            x, table0, wh0, wx1, wh1, b1, why, by, out);
        return;
    }

    float* h0st   = wsf + tabF;
    float* c0st   = h0st + (size_t)B_ * H_;
    float* h1st   = c0st + (size_t)B_ * H_;
    float* c1st   = h1st + (size_t)B_ * H_;
    float* h0buf  = c1st + (size_t)B_ * H_;
    float* xg1buf = h0buf + (size_t)B_ * TC * H_;
    float* h1buf  = xg1buf + (size_t)B_ * TC * G4;

    hipMemsetAsync(h0st, 0, stateF * sizeof(float), stream);

    const int NC = T_ / TC;
    for (int c = 0; c < NC; ++c) {
        const int t0 = c * TC;
        lstm_l0_chunk<<<dim3(B_), dim3(1024), 0, stream>>>(
            x, table0, wh0, h0st, c0st, h0buf, t0, TC);
        gemm_xg1<<<dim3(4 * TC), dim3(G4), 0, stream>>>(
            h0buf, wx1, b1, xg1buf);
        lstm_l1_chunk<<<dim3(B_), dim3(1024), 0, stream>>>(
            xg1buf, wh1, h1st, c1st, h1buf, TC);
        proj_y<<<dim3(B_), dim3(256), 0, stream>>>(
            h1buf, why, by, out, t0, TC);
    }
}